// Round 5
// baseline (446.926 us; speedup 1.0000x reference)
//
#include <hip/hip_runtime.h>
#include <math.h>

typedef __attribute__((ext_vector_type(8))) short short8;
typedef __attribute__((ext_vector_type(4))) float float4v;
typedef __attribute__((ext_vector_type(16))) float float16v;
typedef __attribute__((ext_vector_type(4))) unsigned short ushort4v;
typedef unsigned short u16;
typedef unsigned int u32;

#define NB 64
#define NN 2048
#define FD 128
#define UD 64
#define KT 384

// ---- PANEL FORMAT ----
// matrix[row][k] -> flat[(rowgrp*KGRPS + kgrp)*1024 + (((k>>3)&3)*32 + (row&31))*8 + (k&7)]
// 32x32 panel = 2KB contiguous; slot order == MFMA fragment order (lane=row, 16B/lane).
// Chebyshev fold: proj uses W0'=W0-W2, W1, W2'=2*W2 so only Y=A@X1 (not X2) is needed.

__device__ __forceinline__ u16 f2bf(float f) {
    unsigned int u = __float_as_uint(f);
    u += 0x7fffu + ((u >> 16) & 1u);
    return (u16)(u >> 16);
}
__device__ __forceinline__ float bf2f(u16 s) {
    return __uint_as_float(((unsigned int)s) << 16);
}
__device__ __forceinline__ float sigmoidf_(float x) {
    return 1.0f / (1.0f + expf(-x));
}
__device__ __forceinline__ void gl2lds16(const u16* g, u16* l) {
    __builtin_amdgcn_global_load_lds((const __attribute__((address_space(1))) unsigned int*)g,
                                     (__attribute__((address_space(3))) unsigned int*)l,
                                     16, 0, 0);
}

// ---------------------------------------------------------------- merged prep
// blocks [0,2048): rownorm | [2048,2240): reorderW ru | [2240,2336): reorderW c | [2336,3360): xcat
__global__ void k_prep(const float* __restrict__ adj, float* __restrict__ d_inv,
                       const float* __restrict__ W_ru, u16* __restrict__ Wru,
                       const float* __restrict__ W_c,  u16* __restrict__ Wc,
                       const float* __restrict__ x, const float* __restrict__ h,
                       u16* __restrict__ X0f, u16* __restrict__ X0m) {
    __shared__ u16 T[128 * 136];
    int bid = blockIdx.x;
    int t = threadIdx.x;
    if (bid < 2048) {
        // ---- rownorm
        int m = bid;
        const float4v* row = (const float4v*)(adj + (size_t)m * NN);
        float s = 0.f;
        for (int i = t; i < NN / 4; i += 256) {
            float4v v = row[i];
            s += v.x + v.y + v.z + v.w;
        }
        float* red = (float*)T;
        for (int off = 32; off; off >>= 1) s += __shfl_down(s, off, 64);
        if ((t & 63) == 0) red[t >> 6] = s;
        __syncthreads();
        if (t == 0) {
            float tt = red[0] + red[1] + red[2] + red[3] + 1.0f;
            d_inv[m] = 1.0f / tt;
        }
        return;
    }
    if (bid < 2336) {
        // ---- reorderW (Chebyshev-folded)
        const float* W; u16* Wt; int OD, idx;
        if (bid < 2240) { W = W_ru; Wt = Wru; OD = FD; idx = (bid - 2048) * 256 + t; }
        else            { W = W_c;  Wt = Wc;  OD = UD; idx = (bid - 2240) * 256 + t; }
        if (idx >= KT * OD) return;
        int o  = idx % OD;
        int kp = idx / OD;
        int kd = kp >> 7, f = kp & 127;
        float v;
        if (kd == 0)      v = W[(size_t)(f * 3 + 0) * OD + o] - W[(size_t)(f * 3 + 2) * OD + o];
        else if (kd == 1) v = W[(size_t)(f * 3 + 1) * OD + o];
        else              v = 2.0f * W[(size_t)(f * 3 + 2) * OD + o];
        size_t dst = ((size_t)(o >> 5) * 12 + (kp >> 5)) * 1024 + (((kp >> 3) & 3) * 32 + (o & 31)) * 8 + (kp & 7);
        Wt[dst] = f2bf(v);
        return;
    }
    // ---- xcat
    int rb = bid - 2336;
    int m0 = (rb & 15) * 128;
    int b  = rb >> 4;
    const float* srcs[2] = { x + (size_t)b * (NN * 64), h + (size_t)b * (NN * 64) };
    for (int s = 0; s < 2; ++s) {
        const float* src = srcs[s];
        for (int p = 0; p < 8; ++p) {
            int idx = t + 256 * p;
            int mi = idx >> 4;
            int f4 = idx & 15;
            float4v v = *(const float4v*)(src + (size_t)(m0 + mi) * 64 + f4 * 4);
            float vv[4] = {v.x, v.y, v.z, v.w};
#pragma unroll
            for (int j = 0; j < 4; ++j)
                T[(s * 64 + f4 * 4 + j) * 136 + mi] = f2bf(vv[j]);
        }
    }
    __syncthreads();
#pragma unroll
    for (int p = 0; p < 8; ++p) {
        int S = t + 256 * p;
        int fgl = S >> 9, kgl = (S >> 7) & 3, s = S & 127;
        int c = s >> 5, r = s & 31;
        short8 v = *(const short8*)(T + (fgl * 32 + r) * 136 + kgl * 32 + c * 8);
        *(short8*)(X0f + ((size_t)(b * 4 + fgl) * 64 + (m0 >> 5) + kgl) * 1024 + s * 8) = v;
    }
#pragma unroll
    for (int p = 0; p < 8; ++p) {
        int S = t + 256 * p;
        int fc = S >> 7;
        int mi = S & 127;
        short8 v;
#pragma unroll
        for (int e = 0; e < 8; ++e) v[e] = (short)T[(fc * 8 + e) * 136 + mi];
        size_t dst = ((size_t)(b * 64 + (m0 >> 5) + (mi >> 5)) * 4 + (fc >> 2)) * 1024
                     + ((fc & 3) * 32 + (mi & 31)) * 8;
        *(short8*)(X0m + dst) = v;
    }
}

// ---------------------------------------------------------------- adjT panels (rows n, k=m)
__global__ void k_adjT(const float* __restrict__ adj, const float* __restrict__ d_inv,
                       u16* __restrict__ adjT) {
    __shared__ u16 T[64 * 72];
    int m0 = blockIdx.x * 64;
    int n0 = blockIdx.y * 64;
    int t = threadIdx.x;
    for (int p = 0; p < 4; ++p) {
        int idx = t + 256 * p;
        int i  = idx >> 4;
        int n4 = idx & 15;
        int m = m0 + i;
        float4v v = *(const float4v*)(adj + (size_t)m * NN + n0 + n4 * 4);
        float di = d_inv[m];
        float vv[4] = {v.x, v.y, v.z, v.w};
#pragma unroll
        for (int j = 0; j < 4; ++j) {
            int n = n0 + n4 * 4 + j;
            float a = vv[j] + ((m == n) ? 1.0f : 0.0f);
            T[(n4 * 4 + j) * 72 + i] = f2bf(a * di);
        }
    }
    __syncthreads();
#pragma unroll
    for (int p = 0; p < 2; ++p) {
        int S = t + 256 * p;
        int rgl = S >> 8, kgl = (S >> 7) & 1, s = S & 127;
        int c = s >> 5, r = s & 31;
        short8 v = *(const short8*)(T + (rgl * 32 + r) * 72 + kgl * 32 + c * 8);
        *(short8*)(adjT + ((size_t)((n0 >> 5) + rgl) * 64 + (m0 >> 5) + kgl) * 1024 + s * 8) = v;
    }
}

// ---------------------------------------------------------------- GEMM 256x256 tile, 8-wave, B-DIRECT pipeline
// Diagnosis r0-r4: all schedules pin at ~37% MfmaUtil because per tile the CU pushes
// 96KB fragment ds_reads + 32KB staging writes = 128KB through one LDS (~85 B/cyc eff
// -> ~1540cyc) with read->MFMA dependencies; MFMA needs only 1033cyc. Fix: take the
// B-operand (adjT) OUT of LDS. Panel format makes each fb fragment a 64-lane x 16B
// contiguous global_load_dwordx4 -> registers (double-buffered, prefetched 1 K-tile
// ahead; latency hides under the tile body). LDS now stages only A (cols): 16KB/tile,
// quad-buffered 64KB, depth-3, counted vmcnt by exact issue-order arithmetic.
// LDS traffic/tile: 128KB -> 80KB (below MFMA 1033cyc -> pipe can be the limiter).
// XCD mapping: each XCD owns 4 col-blocks (4MB X slice, L2-resident); adjT streams from L2/L3.
#define GSTEP5(KT, C00, C01, C10, C11, N00, N01, N10, N11)                     \
  {                                                                            \
    if ((KT) < 63) {                                                           \
      size_t fo = (size_t)((KT) + 1) * 1024;                                   \
      N00 = *(const short8*)(gF0 + fo);                                        \
      N01 = *(const short8*)(gF0 + fo + 512);                                  \
      N10 = *(const short8*)(gF1 + fo);                                        \
      N11 = *(const short8*)(gF1 + fo + 512);                                  \
    }                                                                          \
    if ((KT) < 61) {                                                           \
      size_t ko = (size_t)((KT) + 3) * 1024;                                   \
      u16* sb = SM + (((KT) + 3) & 3) * 8192;                                  \
      gl2lds16(gA[0] + ko, sb + la[0]);                                        \
      gl2lds16(gA[1] + ko, sb + la[1]);                                        \
    }                                                                          \
    __builtin_amdgcn_sched_barrier(0);                                         \
    u16* rb_ = SM + ((KT) & 3) * 8192;                                         \
    short8 fa[4];                                                              \
    _Pragma("unroll") for (int mt = 0; mt < 4; ++mt)                           \
      fa[mt] = *(const short8*)(rb_ + rdA + mt * 1024);                        \
    __builtin_amdgcn_s_setprio(1);                                             \
    _Pragma("unroll") for (int mt = 0; mt < 4; ++mt) {                         \
      acc[mt][0] = __builtin_amdgcn_mfma_f32_32x32x16_bf16(fa[mt], C00, acc[mt][0], 0, 0, 0); \
      acc[mt][1] = __builtin_amdgcn_mfma_f32_32x32x16_bf16(fa[mt], C10, acc[mt][1], 0, 0, 0); \
    }                                                                          \
    __builtin_amdgcn_s_setprio(0);                                             \
    _Pragma("unroll") for (int mt = 0; mt < 4; ++mt)                           \
      fa[mt] = *(const short8*)(rb_ + rdA + mt * 1024 + 512);                  \
    __builtin_amdgcn_s_setprio(1);                                             \
    _Pragma("unroll") for (int mt = 0; mt < 4; ++mt) {                         \
      acc[mt][0] = __builtin_amdgcn_mfma_f32_32x32x16_bf16(fa[mt], C01, acc[mt][0], 0, 0, 0); \
      acc[mt][1] = __builtin_amdgcn_mfma_f32_32x32x16_bf16(fa[mt], C11, acc[mt][1], 0, 0, 0); \
    }                                                                          \
    __builtin_amdgcn_s_setprio(0);                                             \
    if ((KT) < 61)       asm volatile("s_waitcnt vmcnt(12)" ::: "memory");     \
    else if ((KT) == 61) asm volatile("s_waitcnt vmcnt(10)" ::: "memory");     \
    else if ((KT) == 62) asm volatile("s_waitcnt vmcnt(8)"  ::: "memory");     \
    if ((KT) < 63) {                                                           \
      __builtin_amdgcn_s_barrier();                                            \
      __builtin_amdgcn_sched_barrier(0);                                       \
    }                                                                          \
  }

template<int HAS_F>
__global__ __launch_bounds__(512, 2)
void k_gemm256(const u16* __restrict__ Ap, const u16* __restrict__ Bc,
               u16* __restrict__ outF, u16* __restrict__ outM) {
    __shared__ __align__(16) u16 SM[34816];   // 4 A-bufs x 8 panels x 1024 = 32768; epilogue needs 34816
    int bid = blockIdx.x;
    int wxcd = bid >> 3;
    int cb = (bid & 7) * 4 + (wxcd & 3);   // 4 col-blocks per XCD -> X slice L2-resident
    int nb = wxcd >> 2;                    // node blocks stream (adjT from L2/L3)
    int n0 = nb * 256, c0 = cb * 256;
    int t = threadIdx.x;
    int wave = t >> 6, lane = t & 63;
    int wx = wave >> 2;          // col half (0..1)
    int wy = wave & 3;           // node quarter (0..3)
    int ln = lane & 31, hi = lane >> 5;

    // A staging: per K-tile = 16KB (8 col panels) = 2 issues/thread
    const u16* gA[2];
    int la[2];
#pragma unroll
    for (int i = 0; i < 2; ++i) {
        int idx = i * 512 + t;
        int p = idx >> 7, s = idx & 127;
        gA[i] = Bc + ((size_t)((c0 >> 5) + p) * 64) * 1024 + s * 8;
        la[i] = idx * 8;
    }
    // B fragments: direct global, per-lane 16B contiguous (coalesced 1KB/wave)
    const u16* gF0 = Ap + ((size_t)((n0 >> 5) + wy * 2 + 0) * 64) * 1024 + lane * 8;
    const u16* gF1 = Ap + ((size_t)((n0 >> 5) + wy * 2 + 1) * 64) * 1024 + lane * 8;

    float16v acc[4][2];
#pragma unroll
    for (int mt = 0; mt < 4; ++mt)
#pragma unroll
        for (int nt = 0; nt < 2; ++nt)
#pragma unroll
            for (int e = 0; e < 16; ++e) acc[mt][nt][e] = 0.f;

    int rdA = wx * 4096 + lane * 8;          // col panels wx*4+mt

    // prologue: stage A tiles 0,1,2 -> bufs 0,1,2; load fb(0); wait A(0) only
#pragma unroll
    for (int tt = 0; tt < 3; ++tt) {
        gl2lds16(gA[0] + tt * 1024, SM + tt * 8192 + la[0]);
        gl2lds16(gA[1] + tt * 1024, SM + tt * 8192 + la[1]);
    }
    short8 C00, C01, C10, C11, N00, N01, N10, N11;
    C00 = *(const short8*)(gF0);
    C01 = *(const short8*)(gF0 + 512);
    C10 = *(const short8*)(gF1);
    C11 = *(const short8*)(gF1 + 512);
    asm volatile("s_waitcnt vmcnt(8)" ::: "memory");   // A(0) done; A(1,2)+fb(0) in flight
    __builtin_amdgcn_s_barrier();
    __builtin_amdgcn_sched_barrier(0);

    for (int i = 0; i < 32; ++i) {
        GSTEP5(2 * i,     C00, C01, C10, C11, N00, N01, N10, N11);
        GSTEP5(2 * i + 1, N00, N01, N10, N11, C00, C01, C10, C11);
    }

    // ---- m-major direct panel writes (identical mapping to 128^2 kernel)
    int batch0 = cb * 2 + wx;                 // FD=128 -> col half == batch
#pragma unroll
    for (int mt = 0; mt < 4; ++mt) {
#pragma unroll
        for (int nt = 0; nt < 2; ++nt) {
            int mg = (n0 >> 5) + wy * 2 + nt;
            size_t pbase = ((size_t)(batch0 * 64 + mg) * 4 + mt) * 1024;
#pragma unroll
            for (int eq = 0; eq < 4; ++eq) {
                ushort4v pk;
#pragma unroll
                for (int r = 0; r < 4; ++r) pk[r] = f2bf(acc[mt][nt][eq * 4 + r]);
                *(ushort4v*)(outM + pbase + (eq * 32 + ln) * 8 + 4 * hi) = pk;
            }
        }
    }

    // ---- optional f-major panels via LDS transpose (two node-halves of 128)
    if (HAS_F) {
#pragma unroll
        for (int p = 0; p < 2; ++p) {
            __syncthreads();
            if ((wy >> 1) == p) {
#pragma unroll
                for (int mt = 0; mt < 4; ++mt)
#pragma unroll
                    for (int nt = 0; nt < 2; ++nt)
#pragma unroll
                        for (int e = 0; e < 16; ++e) {
                            int cl = wx * 128 + mt * 32 + 4 * hi + 8 * (e >> 2) + (e & 3);
                            int nl = (wy & 1) * 64 + nt * 32 + ln;
                            SM[cl * 136 + nl] = f2bf(acc[mt][nt][e]);
                        }
            }
            __syncthreads();
#pragma unroll
            for (int j = 0; j < 8; ++j) {
                int S = t + 512 * j;              // 4096 short8 = 256 cols x 128 nodes
                int col = S >> 4, nd8 = S & 15;
                short8 v = *(const short8*)(SM + col * 136 + nd8 * 8);
                int gn = n0 + p * 128 + nd8 * 8;
                size_t dst = ((size_t)((c0 >> 5) + (col >> 5)) * 64 + (gn >> 5)) * 1024
                             + (size_t)((((gn >> 3) & 3) * 32 + (col & 31))) * 8;
                *(short8*)(outF + dst) = v;
            }
        }
    }
}

// ---------------------------------------------------------------- GEMM, 128x128 tile, 32x32x16 MFMA, 4 blocks/CU
template<int FG>
__global__ __launch_bounds__(256, 4)
void k_gemm(const u16* __restrict__ A, const u16* __restrict__ Bc,
            u16* __restrict__ outF, u16* __restrict__ outM, int cBlocks) {
    __shared__ u16 SM[16384];
    u16* A0 = SM;            u16* A1 = SM + 4096;
    u16* B0 = SM + 8192;     u16* B1 = SM + 12288;

    int id = blockIdx.x + cBlocks * blockIdx.y;
    int band = cBlocks >> 3;
    int g = id & 7, s = id >> 3;
    int cb = g * band + (s % band);
    int nb = s / band;
    int c0 = cb * 128;
    int n0 = nb * 128;

    int t = threadIdx.x;
    int wave = t >> 6, lane = t & 63;
    int wy = wave & 1, wx = wave >> 1;
    int ln = lane & 31, hi = lane >> 5;
    int l16 = lane * 8;

    const u16* gaP[2];
    const u16* gbP[2];
#pragma unroll
    for (int i = 0; i < 2; ++i) {
        int T = t + 256 * i;
        gaP[i] = A  + ((size_t)((n0 >> 5) + (T >> 7)) * 64) * 1024 + (size_t)(T & 127) * 8;
        gbP[i] = Bc + ((size_t)((c0 >> 5) + (T >> 7)) * 64) * 1024 + (size_t)(T & 127) * 8;
    }

    float16v acc[2][2];
#pragma unroll
    for (int i = 0; i < 2; ++i)
#pragma unroll
        for (int j = 0; j < 2; ++j)
#pragma unroll
            for (int e = 0; e < 16; ++e) acc[i][j][e] = 0.f;

#pragma unroll
    for (int i = 0; i < 2; ++i) { gl2lds16(gaP[i], A0 + (t + 256 * i) * 8); gl2lds16(gbP[i], B0 + (t + 256 * i) * 8); }

#pragma unroll 2
    for (int it = 0; it < 64; ++it) {
        u16* Ac = (it & 1) ? A1 : A0;
        u16* Bs = (it & 1) ? B1 : B0;
        __syncthreads();
        if (it + 1 < 64) {
            int ko = (it + 1) * 1024;
            u16* An = (it & 1) ? A0 : A1;
            u16* Bn = (it & 1) ? B0 : B1;
#pragma unroll
            for (int i = 0; i < 2; ++i) { gl2lds16(gaP[i] + ko, An + (t + 256 * i) * 8); gl2lds16(gbP[i] + ko, Bn + (t + 256 * i) * 8); }
        }
        short8 fa[2][2], fb[2][2];
#pragma unroll
        for (int ks = 0; ks < 2; ++ks) {
#pragma unroll
            for (int mt = 0; mt < 2; ++mt)
                fa[ks][mt] = *(const short8*)(Bs + ((wx * 2 + mt) * 2 + ks) * 512 + l16);
#pragma unroll
            for (int nt = 0; nt < 2; ++nt)
                fb[ks][nt] = *(const short8*)(Ac + ((wy * 2 + nt) * 2 + ks) * 512 + l16);
        }
#pragma unroll
        for (int ks = 0; ks < 2; ++ks)
#pragma unroll
            for (int mt = 0; mt < 2; ++mt)
#pragma unroll
                for (int nt = 0; nt < 2; ++nt)
                    acc[mt][nt] = __builtin_amdgcn_mfma_f32_32x32x16_bf16(fa[ks][mt], fb[ks][nt], acc[mt][nt], 0, 0, 0);
    }

    // m-major direct panel writes
#pragma unroll
    for (int mt = 0; mt < 2; ++mt) {
#pragma unroll
        for (int nt = 0; nt < 2; ++nt) {
            int mg = (n0 >> 5) + wy * 2 + nt;
            int batch = (FG == 4) ? cb : (2 * cb + wx);
            int fg = (FG == 4) ? (wx * 2 + mt) : mt;
            size_t pbase = ((size_t)(batch * 64 + mg) * FG + fg) * 1024;
#pragma unroll
            for (int eq = 0; eq < 4; ++eq) {
                ushort4v pk;
#pragma unroll
                for (int r = 0; r < 4; ++r) pk[r] = f2bf(acc[mt][nt][eq * 4 + r]);
                *(ushort4v*)(outM + pbase + (eq * 32 + ln) * 8 + 4 * hi) = pk;
            }
        }
    }

    // optional f-major panels via LDS transpose
    if (outF) {
        __syncthreads();
#pragma unroll
        for (int p = 0; p < 2; ++p) {
            if (p) __syncthreads();
            if (wx == p) {
#pragma unroll
                for (int mt = 0; mt < 2; ++mt)
#pragma unroll
                    for (int nt = 0; nt < 2; ++nt)
#pragma unroll
                        for (int e = 0; e < 16; ++e) {
                            int cl = mt * 32 + 4 * hi + 8 * (e >> 2) + (e & 3);
                            int nl = wy * 64 + nt * 32 + ln;
                            SM[cl * 136 + nl] = f2bf(acc[mt][nt][e]);
                        }
            }
            __syncthreads();
#pragma unroll
            for (int pp = 0; pp < 4; ++pp) {
                int S = t + 256 * pp;
                int rgl = S >> 9, kgl = (S >> 7) & 3, sl = S & 127;
                int c = sl >> 5, r = sl & 31;
                short8 v = *(const short8*)(SM + (rgl * 32 + r) * 136 + kgl * 32 + c * 8);
                size_t gaddr = ((size_t)((c0 >> 5) + p * 2 + rgl) * 64 + (n0 >> 5) + kgl) * 1024 + sl * 8;
                *(short8*)(outF + gaddr) = v;
            }
        }
    }
}

// ---------------------------------------------------------------- ru projection: 128m x 128o, K=384, fused sigmoid
__global__ __launch_bounds__(256, 3)
void k_proj_ru(const u16* __restrict__ X0m, const u16* __restrict__ X1m, const u16* __restrict__ Ym,
               const u16* __restrict__ Wp, const float* __restrict__ bias, const float* __restrict__ hx,
               u16* __restrict__ RH0f, u16* __restrict__ RH0m, u16* __restrict__ Ut) {
    __shared__ u16 SM[16384];
    u16 *Xa = SM, *Xb = SM + 4096, *Wa = SM + 8192, *Wb = SM + 12288;
    int mb = blockIdx.x, b = blockIdx.y;
    int m0 = mb * 128, mg0 = mb * 4;
    int t = threadIdx.x, wave = t >> 6, lane = t & 63;
    int wx = wave & 1, wyy = wave >> 1;
    int ln = lane & 31, hi = lane >> 5;
    const u16* Xs[3] = {X0m, X1m, Ym};
    int p0 = t >> 7, s0 = t & 127;

    float16v acc[2][2];
#pragma unroll
    for (int i = 0; i < 2; ++i)
#pragma unroll
        for (int j = 0; j < 2; ++j)
#pragma unroll
            for (int e = 0; e < 16; ++e) acc[i][j][e] = 0.f;

    gl2lds16(Xs[0] + ((size_t)((b * 64 + mg0 + p0) * 4)) * 1024 + s0 * 8, Xa + t * 8);
    gl2lds16(Xs[0] + ((size_t)((b * 64 + mg0 + p0 + 2) * 4)) * 1024 + s0 * 8, Xa + (t + 256) * 8);
    gl2lds16(Wp + ((size_t)(p0 * 12)) * 1024 + s0 * 8, Wa + t * 8);
    gl2lds16(Wp + ((size_t)((p0 + 2) * 12)) * 1024 + s0 * 8, Wa + (t + 256) * 8);

    for (int kq = 0; kq < 12; ++kq) {
        u16* Xc = (kq & 1) ? Xb : Xa;
        u16* Wc = (kq & 1) ? Wb : Wa;
        __syncthreads();
        if (kq + 1 < 12) {
            int k2 = kq + 1, kd = k2 >> 2, kg = k2 & 3;
            u16* Xn = (kq & 1) ? Xa : Xb;
            u16* Wn = (kq & 1) ? Wa : Wb;
            const u16* xb = Xs[kd];
            gl2lds16(xb + ((size_t)((b * 64 + mg0 + p0) * 4 + kg)) * 1024 + s0 * 8, Xn + t * 8);
            gl2lds16(xb + ((size_t)((b * 64 + mg0 + p0 + 2) * 4 + kg)) * 1024 + s0 * 8, Xn + (t + 256) * 8);
            gl2lds16(Wp + ((size_t)(p0 * 12 + k2)) * 1024 + s0 * 8, Wn + t * 8);
            gl2lds16(Wp + ((size_t)((p0 + 2) * 12 + k2)) * 1024 + s0 * 8, Wn + (t + 256) * 8);
        }
        short8 fa[2][2], fb[2][2];
#pragma unroll
        for (int ks = 0; ks < 2; ++ks) {
#pragma unroll
            for (int mt = 0; mt < 2; ++mt)
                fa[ks][mt] = *(const short8*)(Xc + ((wx * 2 + mt) * 2 + ks) * 512 + lane * 8);
#pragma unroll
            for (int nt = 0; nt < 2; ++nt)
                fb[ks][nt] = *(const short8*)(Wc + ((wyy * 2 + nt) * 2 + ks) * 512 + lane * 8);
        }
#pragma unroll
        for (int ks = 0; ks < 2; ++ks)
#pragma unroll
            for (int mt = 0; mt < 2; ++mt)
#pragma unroll
                for (int nt = 0; nt < 2; ++nt)
                    acc[mt][nt] = __builtin_amdgcn_mfma_f32_32x32x16_bf16(fa[ks][mt], fb[ks][nt], acc[mt][nt], 0, 0, 0);
    }
    __syncthreads();
    if (wyy == 0) {
#pragma unroll
        for (int mt = 0; mt < 2; ++mt)
#pragma unroll
            for (int nt = 0; nt < 2; ++nt) {
                int o = nt * 32 + ln;
                float bo = bias[o];
                u16 vals[16];
#pragma unroll
                for (int e = 0; e < 16; ++e) {
                    int ml = wx * 64 + mt * 32 + 4 * hi + 8 * (e >> 2) + (e & 3);
                    float sg = sigmoidf_(acc[mt][nt][e] + bo);
                    float hh = hx[((size_t)b * NN + m0 + ml) * 64 + o];
                    vals[e] = f2bf(sg * hh);
                    SM[ml * 76 + o] = vals[e];
                }
#pragma unroll
                for (int eq = 0; eq < 4; ++eq) {
                    ushort4v pk;
#pragma unroll
                    for (int r = 0; r < 4; ++r) pk[r] = vals[eq * 4 + r];
                    size_t addr = ((size_t)(b * 2 + nt) * 64 + mg0 + wx * 2 + mt) * 1024 + (eq * 32 + ln) * 8 + 4 * hi;
                    *(ushort4v*)(RH0f + addr) = pk;
                }
            }
    } else {
#pragma unroll
        for (int mt = 0; mt < 2; ++mt)
#pragma unroll
            for (int nt = 0; nt < 2; ++nt) {
                int og = nt * 32 + ln;
                float bo = bias[64 + og];
#pragma unroll
                for (int e = 0; e < 16; ++e) {
                    int ml = wx * 64 + mt * 32 + 4 * hi + 8 * (e >> 2) + (e & 3);
                    Ut[((size_t)b * NN + m0 + ml) * 64 + og] = f2bf(sigmoidf_(acc[mt][nt][e] + bo));
                }
            }
    }
    __syncthreads();
#pragma unroll
    for (int j = 0; j < 4; ++j) {
        int C = t + 256 * j;
        int p = C >> 7, sl = C & 127;
        int mgl = p >> 1, ug = p & 1;
        int cq = sl >> 5, r = sl & 31;
        short8 v = *(const short8*)(SM + (mgl * 32 + r) * 76 + ug * 32 + cq * 8);
        *(short8*)(RH0m + ((size_t)((b * 64 + mg0 + mgl) * 2 + ug)) * 1024 + sl * 8) = v;
    }
}

// ---------------------------------------------------------------- c projection: 128m x 64o, K=384, fused tanh + combine
__global__ __launch_bounds__(256, 4)
void k_proj_c(const u16* __restrict__ X0m, const u16* __restrict__ X1m, const u16* __restrict__ Ym,
              const u16* __restrict__ RH0m, const u16* __restrict__ RH1m, const u16* __restrict__ Zm,
              const u16* __restrict__ Wp, const float* __restrict__ bias,
              const float* __restrict__ hx, const u16* __restrict__ Ut,
              float* __restrict__ out) {
    __shared__ u16 SM[12288];
    u16 *Xa = SM, *Xb = SM + 4096, *Wa = SM + 8192, *Wb = SM + 10240;
    int mb = blockIdx.x, b = blockIdx.y;
    int m0 = mb * 128, mg0 = mb * 4;
    int t = threadIdx.x, wave = t >> 6, lane = t & 63;
    int wx = wave & 1, wyy = wave >> 1;
    int ln = lane & 31, hi = lane >> 5;
    const u16* Xs[3] = {X0m, X1m, Ym};
    const u16* Rs[3] = {RH0m, RH1m, Zm};
    int p0 = t >> 7, s0 = t & 127;

    float16v acc[2];
#pragma unroll
    for (int i = 0; i < 2; ++i)
#pragma unroll
        for (int e = 0; e < 16; ++e) acc[i][e] = 0.f;

    gl2lds16(Xs[0] + ((size_t)((b * 64 + mg0 + p0) * 4)) * 1024 + s0 * 8, Xa + t * 8);
    gl2lds16(Xs[0] + ((size_t)((b * 64 + mg0 + p0 + 2) * 4)) * 1024 + s0 * 8, Xa + (t + 256) * 8);
    gl2lds16(Wp + ((size_t)(p0 * 12)) * 1024 + s0 * 8, Wa + t * 8);

    for (int kq = 0; kq < 12; ++kq) {
        u16* Xc = (kq & 1) ? Xb : Xa;
        u16* Wc = (kq & 1) ? Wb : Wa;
        __syncthreads();
        if (kq + 1 < 12) {
            int k2 = kq + 1, kd = k2 >> 2, fb2 = (k2 & 3) * 32;
            u16* Xn = (kq & 1) ? Xa : Xb;
            u16* Wn = (kq & 1) ? Wa : Wb;
            const u16* mat; size_t pb0, pb1;
            if (fb2 < 64) {
                mat = Xs[kd];
                pb0 = ((size_t)((b * 64 + mg0 + p0) * 4 + (fb2 >> 5))) * 1024;
                pb1 = ((size_t)((b * 64 + mg0 + p0 + 2) * 4 + (fb2 >> 5))) * 1024;
            } else {
                mat = Rs[kd];
                pb0 = ((size_t)((b * 64 + mg0 + p0) * 2 + ((fb2 >> 5) - 2))) * 1024;
                pb1 = ((size_t)((b * 64 + mg0 + p0 + 2) * 2 + ((fb2 >> 5) - 2))) * 1024;
            }
            gl2lds16(mat + pb0 + s0 * 8, Xn + t * 8);
            gl2lds16(mat + pb1 + s0 * 8, Xn + (t + 256) * 8);
            gl2lds16(Wp + ((size_t)(p0 * 12 + k2)) * 1024 + s0 * 8, Wn + t * 8);
        }
        short8 fa[2][2], fbg[2];
#pragma unroll
        for (int ks = 0; ks < 2; ++ks) {
#pragma unroll
            for (int mt = 0; mt < 2; ++mt)
                fa[ks][mt] = *(const short8*)(Xc + ((wx * 2 + mt) * 2 + ks) * 512 + lane * 8);
            fbg[ks] = *(const short8*)(Wc + (wyy * 2 + ks) * 512 + lane * 8);
        }
#pragma unroll
        for (int ks = 0; ks < 2; ++ks)
#pragma unroll
            for (int mt = 0; mt < 2; ++mt)
                acc[mt] = __builtin_amdgcn_mfma_f32_32x32x16_bf16(fa[ks][mt], fbg[ks], acc[mt], 0, 0, 0);
    }
    int o = wyy * 32 + ln;
    float bo = bias[o];
#pragma unroll
    for (int mt = 0; mt < 2; ++mt)
#pragma unroll
        for (int e = 0; e < 16; ++e) {
            int ml = wx * 64 + mt * 32 + 4 * hi + 8 * (e >> 2) + (e & 3);
            size_t idx = ((size_t)b * NN + m0 + ml) * 64 + o;
            float c = tanhf(acc[mt][e] + bo);
            float u = bf2f(Ut[idx]);
            float hh = hx[idx];
            out[idx] = u * hh + (1.0f - u) * c;
        }
}

// ---------------------------------------------------------------- launch
extern "C" void kernel_launch(void* const* d_in, const int* in_sizes, int n_in,
                              void* d_out, int out_size, void* d_ws, size_t ws_size,
                              hipStream_t stream) {
    const float* x    = (const float*)d_in[0];
    const float* hx   = (const float*)d_in[1];
    const float* adj  = (const float*)d_in[2];
    const float* W_ru = (const float*)d_in[3];
    const float* b_ru = (const float*)d_in[4];
    const float* W_c  = (const float*)d_in[5];
    const float* b_c  = (const float*)d_in[6];
    float* out = (float*)d_out;

    char* ws = (char*)d_ws;
    size_t off = 0;
    auto alloc = [&](size_t bytes) -> void* {
        void* p = ws + off;
        off += (bytes + 255) & ~(size_t)255;
        return p;
    };
    float* d_inv = (float*)alloc((size_t)NN * 4);
    u16* adjT = (u16*)alloc((size_t)NN * NN * 2);
    u16* Wru  = (u16*)alloc((size_t)FD * KT * 2);
    u16* Wc   = (u16*)alloc((size_t)UD * KT * 2);
    u16* X0f = (u16*)alloc((size_t)NB * FD * NN * 2);   // aliased as RH0f after gemm#1
    u16* X1f = (u16*)alloc((size_t)NB * FD * NN * 2);   // aliased as RH1f after gemm#2
    u16* X0m = (u16*)alloc((size_t)NB * FD * NN * 2);
    u16* X1m = (u16*)alloc((size_t)NB * FD * NN * 2);
    u16* Ym  = (u16*)alloc((size_t)NB * FD * NN * 2);
    u16* RH0m = (u16*)alloc((size_t)NB * UD * NN * 2);
    u16* RH1m = (u16*)alloc((size_t)NB * UD * NN * 2);
    u16* Zm   = (u16*)alloc((size_t)NB * UD * NN * 2);
    u16* Ut   = (u16*)alloc((size_t)NB * UD * NN * 2);
    u16* RH0f = X0f;
    u16* RH1f = X1f;

    // merged prep: rownorm | reorderW(ru) | reorderW(c) | xcat  (all independent)
    k_prep<<<dim3(3360), dim3(256), 0, stream>>>(adj, d_inv, W_ru, Wru, W_c, Wc, x, hx, X0f, X0m);
    k_adjT<<<dim3(32, 32), dim3(256), 0, stream>>>(adj, d_inv, adjT);
    // X1 = A@X0 (dual out); Y = A@X1 (m-major only; Chebyshev folded into W)
    // 256^2-tile B-direct kernels: 256 blocks = exactly 1 wave of the 256-CU grid
    k_gemm256<1><<<dim3(256), dim3(512), 0, stream>>>(adjT, X0f, X1f, X1m);
    k_gemm256<0><<<dim3(256), dim3(512), 0, stream>>>(adjT, X1f, nullptr, Ym);
    k_proj_ru<<<dim3(16, NB), dim3(256), 0, stream>>>(X0m, X1m, Ym, Wru, b_ru, hx, RH0f, RH0m, Ut);
    // RH1 = A@RH0 (dual); Z = A@RH1 (m-major only) — N=4096 -> keep 128^2 kernel (full occupancy)
    k_gemm<2><<<dim3(32, 16), dim3(256), 0, stream>>>(adjT, RH0f, RH1f, RH1m, 32);
    k_gemm<2><<<dim3(32, 16), dim3(256), 0, stream>>>(adjT, RH1f, nullptr, Zm, 32);
    k_proj_c<<<dim3(16, NB), dim3(256), 0, stream>>>(X0m, X1m, Ym, RH0m, RH1m, Zm, Wc, b_c, hx, Ut, out);
}

// Round 6
// 429.382 us; speedup vs baseline: 1.0409x; 1.0409x over previous
//
#include <hip/hip_runtime.h>
#include <math.h>

typedef __attribute__((ext_vector_type(8))) short short8;
typedef __attribute__((ext_vector_type(4))) float float4v;
typedef __attribute__((ext_vector_type(16))) float float16v;
typedef __attribute__((ext_vector_type(4))) unsigned short ushort4v;
typedef unsigned short u16;
typedef unsigned int u32;

#define NB 64
#define NN 2048
#define FD 128
#define UD 64
#define KT 384

// ---- PANEL FORMAT ----
// matrix[row][k] -> flat[(rowgrp*KGRPS + kgrp)*1024 + (((k>>3)&3)*32 + (row&31))*8 + (k&7)]
// 32x32 panel = 2KB contiguous; slot order == MFMA fragment order (lane=row, 16B/lane).
// Chebyshev fold: proj uses W0'=W0-W2, W1, W2'=2*W2 so only Y=A@X1 (not X2) is needed.

__device__ __forceinline__ u16 f2bf(float f) {
    unsigned int u = __float_as_uint(f);
    u += 0x7fffu + ((u >> 16) & 1u);
    return (u16)(u >> 16);
}
__device__ __forceinline__ float bf2f(u16 s) {
    return __uint_as_float(((unsigned int)s) << 16);
}
__device__ __forceinline__ float sigmoidf_(float x) {
    return 1.0f / (1.0f + expf(-x));
}
__device__ __forceinline__ void gl2lds16(const u16* g, u16* l) {
    __builtin_amdgcn_global_load_lds((const __attribute__((address_space(1))) unsigned int*)g,
                                     (__attribute__((address_space(3))) unsigned int*)l,
                                     16, 0, 0);
}

// ---------------------------------------------------------------- merged prep
// blocks [0,2048): rownorm | [2048,2240): reorderW ru | [2240,2336): reorderW c | [2336,3360): xcat
__global__ void k_prep(const float* __restrict__ adj, float* __restrict__ d_inv,
                       const float* __restrict__ W_ru, u16* __restrict__ Wru,
                       const float* __restrict__ W_c,  u16* __restrict__ Wc,
                       const float* __restrict__ x, const float* __restrict__ h,
                       u16* __restrict__ X0f, u16* __restrict__ X0m) {
    __shared__ u16 T[128 * 136];
    int bid = blockIdx.x;
    int t = threadIdx.x;
    if (bid < 2048) {
        // ---- rownorm
        int m = bid;
        const float4v* row = (const float4v*)(adj + (size_t)m * NN);
        float s = 0.f;
        for (int i = t; i < NN / 4; i += 256) {
            float4v v = row[i];
            s += v.x + v.y + v.z + v.w;
        }
        float* red = (float*)T;
        for (int off = 32; off; off >>= 1) s += __shfl_down(s, off, 64);
        if ((t & 63) == 0) red[t >> 6] = s;
        __syncthreads();
        if (t == 0) {
            float tt = red[0] + red[1] + red[2] + red[3] + 1.0f;
            d_inv[m] = 1.0f / tt;
        }
        return;
    }
    if (bid < 2336) {
        // ---- reorderW (Chebyshev-folded)
        const float* W; u16* Wt; int OD, idx;
        if (bid < 2240) { W = W_ru; Wt = Wru; OD = FD; idx = (bid - 2048) * 256 + t; }
        else            { W = W_c;  Wt = Wc;  OD = UD; idx = (bid - 2240) * 256 + t; }
        if (idx >= KT * OD) return;
        int o  = idx % OD;
        int kp = idx / OD;
        int kd = kp >> 7, f = kp & 127;
        float v;
        if (kd == 0)      v = W[(size_t)(f * 3 + 0) * OD + o] - W[(size_t)(f * 3 + 2) * OD + o];
        else if (kd == 1) v = W[(size_t)(f * 3 + 1) * OD + o];
        else              v = 2.0f * W[(size_t)(f * 3 + 2) * OD + o];
        size_t dst = ((size_t)(o >> 5) * 12 + (kp >> 5)) * 1024 + (((kp >> 3) & 3) * 32 + (o & 31)) * 8 + (kp & 7);
        Wt[dst] = f2bf(v);
        return;
    }
    // ---- xcat
    int rb = bid - 2336;
    int m0 = (rb & 15) * 128;
    int b  = rb >> 4;
    const float* srcs[2] = { x + (size_t)b * (NN * 64), h + (size_t)b * (NN * 64) };
    for (int s = 0; s < 2; ++s) {
        const float* src = srcs[s];
        for (int p = 0; p < 8; ++p) {
            int idx = t + 256 * p;
            int mi = idx >> 4;
            int f4 = idx & 15;
            float4v v = *(const float4v*)(src + (size_t)(m0 + mi) * 64 + f4 * 4);
            float vv[4] = {v.x, v.y, v.z, v.w};
#pragma unroll
            for (int j = 0; j < 4; ++j)
                T[(s * 64 + f4 * 4 + j) * 136 + mi] = f2bf(vv[j]);
        }
    }
    __syncthreads();
#pragma unroll
    for (int p = 0; p < 8; ++p) {
        int S = t + 256 * p;
        int fgl = S >> 9, kgl = (S >> 7) & 3, s = S & 127;
        int c = s >> 5, r = s & 31;
        short8 v = *(const short8*)(T + (fgl * 32 + r) * 136 + kgl * 32 + c * 8);
        *(short8*)(X0f + ((size_t)(b * 4 + fgl) * 64 + (m0 >> 5) + kgl) * 1024 + s * 8) = v;
    }
#pragma unroll
    for (int p = 0; p < 8; ++p) {
        int S = t + 256 * p;
        int fc = S >> 7;
        int mi = S & 127;
        short8 v;
#pragma unroll
        for (int e = 0; e < 8; ++e) v[e] = (short)T[(fc * 8 + e) * 136 + mi];
        size_t dst = ((size_t)(b * 64 + (m0 >> 5) + (mi >> 5)) * 4 + (fc >> 2)) * 1024
                     + ((fc & 3) * 32 + (mi & 31)) * 8;
        *(short8*)(X0m + dst) = v;
    }
}

// ---------------------------------------------------------------- adjT panels (rows n, k=m)
__global__ void k_adjT(const float* __restrict__ adj, const float* __restrict__ d_inv,
                       u16* __restrict__ adjT) {
    __shared__ u16 T[64 * 72];
    int m0 = blockIdx.x * 64;
    int n0 = blockIdx.y * 64;
    int t = threadIdx.x;
    for (int p = 0; p < 4; ++p) {
        int idx = t + 256 * p;
        int i  = idx >> 4;
        int n4 = idx & 15;
        int m = m0 + i;
        float4v v = *(const float4v*)(adj + (size_t)m * NN + n0 + n4 * 4);
        float di = d_inv[m];
        float vv[4] = {v.x, v.y, v.z, v.w};
#pragma unroll
        for (int j = 0; j < 4; ++j) {
            int n = n0 + n4 * 4 + j;
            float a = vv[j] + ((m == n) ? 1.0f : 0.0f);
            T[(n4 * 4 + j) * 72 + i] = f2bf(a * di);
        }
    }
    __syncthreads();
#pragma unroll
    for (int p = 0; p < 2; ++p) {
        int S = t + 256 * p;
        int rgl = S >> 8, kgl = (S >> 7) & 1, s = S & 127;
        int c = s >> 5, r = s & 31;
        short8 v = *(const short8*)(T + (rgl * 32 + r) * 72 + kgl * 32 + c * 8);
        *(short8*)(adjT + ((size_t)((n0 >> 5) + rgl) * 64 + (m0 >> 5) + kgl) * 1024 + s * 8) = v;
    }
}

// ---------------------------------------------------------------- GEMM 256x256 tile, 8-wave, DEEP counted-vmcnt pipeline
// r0-r5 matrix: staging mechanism (gl2lds / reg-staged / B-direct), barrier count (1-4/tile),
// and block shape (128^2 x4 / 256^2 x1) are all NULL levers -- everything pins at 875-940 TF.
// Only measured lever: pipeline DEPTH (r2 depth-2 -> r3 depth-3 = -8%). This version: FIVE
// 32KB buffers (160KB LDS, full CU; we are 1 block/CU regardless), staging FOUR tiles ahead,
// vmcnt(12) steady-state gate (16 issues in flight, drain only the tile needed next).
// One barrier per K-tile. XCD mapping: each XCD owns 4 col-blocks (4MB X slice, L2-resident).
template<int HAS_F>
__global__ __launch_bounds__(512, 2)
void k_gemm256(const u16* __restrict__ Ap, const u16* __restrict__ Bc,
               u16* __restrict__ outF, u16* __restrict__ outM) {
    __shared__ __align__(16) u16 SM[81920];   // 5 bufs x (8 col panels + 8 node panels) x 1024
    int bid = blockIdx.x;
    int wxcd = bid >> 3;
    int cb = (bid & 7) * 4 + (wxcd & 3);   // 4 col-blocks per XCD -> X slice L2-resident
    int nb = wxcd >> 2;                    // node blocks stream (adjT from L3, sync'd across XCDs)
    int n0 = nb * 256, c0 = cb * 256;
    int t = threadIdx.x;
    int wave = t >> 6, lane = t & 63;
    int wx = wave >> 2;          // col half (0..1)
    int wy = wave & 3;           // node quarter (0..3)
    int ln = lane & 31, hi = lane >> 5;

    // staging addresses: per K-tile = 32KB (16KB cols + 16KB nodes) = 4 issues/thread
    const u16* gA[2];            // cols operand (Bc)
    const u16* gB[2];            // nodes operand (Ap)
    int la[2], lb[2];
#pragma unroll
    for (int i = 0; i < 2; ++i) {
        int idx = i * 512 + t;
        int p = idx >> 7, s = idx & 127;
        gA[i] = Bc + ((size_t)((c0 >> 5) + p) * 64) * 1024 + s * 8;
        gB[i] = Ap + ((size_t)((n0 >> 5) + p) * 64) * 1024 + s * 8;
        la[i] = idx * 8;
        lb[i] = 8192 + idx * 8;
    }

    float16v acc[4][2];
#pragma unroll
    for (int mt = 0; mt < 4; ++mt)
#pragma unroll
        for (int nt = 0; nt < 2; ++nt)
#pragma unroll
            for (int e = 0; e < 16; ++e) acc[mt][nt][e] = 0.f;

    // prologue: stage tiles 0..3 -> bufs 0..3 (16 issues); wait tile0 only (12 in flight)
#pragma unroll
    for (int tt = 0; tt < 4; ++tt) {
#pragma unroll
        for (int i = 0; i < 2; ++i) gl2lds16(gA[i] + tt * 1024, SM + tt * 16384 + la[i]);
#pragma unroll
        for (int i = 0; i < 2; ++i) gl2lds16(gB[i] + tt * 1024, SM + tt * 16384 + lb[i]);
    }
    asm volatile("s_waitcnt vmcnt(12)" ::: "memory");
    __builtin_amdgcn_s_barrier();
    __builtin_amdgcn_sched_barrier(0);

    int rdA = wx * 4096 + lane * 8;          // col panels wx*4+mt
    int rdB = 8192 + wy * 2048 + lane * 8;   // node panels wy*2+nt

    int cur = 0;
    for (int kt = 0; kt < 64; ++kt) {
        u16* buf = SM + cur * 16384;
        int stg = cur + 4; if (stg >= 5) stg -= 5;   // buffer of tile kt-1 (retired at last barrier)
        u16* sbuf = SM + stg * 16384;
        size_t ko = (size_t)(kt + 4) * 1024;

        short8 fa0[4], fb0[2], fa1[4], fb1[2];
        // phase-0 fragments first (critical path after barrier)
#pragma unroll
        for (int mt = 0; mt < 4; ++mt) fa0[mt] = *(const short8*)(buf + rdA + mt * 1024);
#pragma unroll
        for (int nt = 0; nt < 2; ++nt) fb0[nt] = *(const short8*)(buf + rdB + nt * 1024);
        // stage tile kt+4 cols
        if (kt < 60) {
#pragma unroll
            for (int i = 0; i < 2; ++i) gl2lds16(gA[i] + ko, sbuf + la[i]);
        }
        // prefetch phase-1 A-fragments under phase-0 MFMA shadow
#pragma unroll
        for (int mt = 0; mt < 4; ++mt) fa1[mt] = *(const short8*)(buf + rdA + mt * 1024 + 512);

        __builtin_amdgcn_s_setprio(1);
#pragma unroll
        for (int mt = 0; mt < 4; ++mt)
#pragma unroll
            for (int nt = 0; nt < 2; ++nt)
                acc[mt][nt] = __builtin_amdgcn_mfma_f32_32x32x16_bf16(fa0[mt], fb0[nt], acc[mt][nt], 0, 0, 0);
        __builtin_amdgcn_s_setprio(0);

#pragma unroll
        for (int nt = 0; nt < 2; ++nt) fb1[nt] = *(const short8*)(buf + rdB + nt * 1024 + 512);
        // stage tile kt+4 nodes
        if (kt < 60) {
#pragma unroll
            for (int i = 0; i < 2; ++i) gl2lds16(gB[i] + ko, sbuf + lb[i]);
        }

        __builtin_amdgcn_s_setprio(1);
#pragma unroll
        for (int mt = 0; mt < 4; ++mt)
#pragma unroll
            for (int nt = 0; nt < 2; ++nt)
                acc[mt][nt] = __builtin_amdgcn_mfma_f32_32x32x16_bf16(fa1[mt], fb1[nt], acc[mt][nt], 0, 0, 0);
        __builtin_amdgcn_s_setprio(0);

        // tile boundary: ensure tile kt+1 landed; keep tiles kt+2..kt+4 (12 issues) in flight
        if (kt < 60)       asm volatile("s_waitcnt vmcnt(12)" ::: "memory");
        else if (kt == 60) asm volatile("s_waitcnt vmcnt(8)"  ::: "memory");
        else if (kt == 61) asm volatile("s_waitcnt vmcnt(4)"  ::: "memory");
        else if (kt == 62) asm volatile("s_waitcnt vmcnt(0)"  ::: "memory");
        if (kt < 63) {
            __builtin_amdgcn_s_barrier();
            __builtin_amdgcn_sched_barrier(0);
        }
        cur = (cur + 1 == 5) ? 0 : cur + 1;
    }

    // ---- m-major direct panel writes (identical mapping to 128^2 kernel)
    int batch0 = cb * 2 + wx;                 // FD=128 -> col half == batch
#pragma unroll
    for (int mt = 0; mt < 4; ++mt) {
#pragma unroll
        for (int nt = 0; nt < 2; ++nt) {
            int mg = (n0 >> 5) + wy * 2 + nt;
            size_t pbase = ((size_t)(batch0 * 64 + mg) * 4 + mt) * 1024;
#pragma unroll
            for (int eq = 0; eq < 4; ++eq) {
                ushort4v pk;
#pragma unroll
                for (int r = 0; r < 4; ++r) pk[r] = f2bf(acc[mt][nt][eq * 4 + r]);
                *(ushort4v*)(outM + pbase + (eq * 32 + ln) * 8 + 4 * hi) = pk;
            }
        }
    }

    // ---- optional f-major panels via LDS transpose (two node-halves of 128)
    if (HAS_F) {
#pragma unroll
        for (int p = 0; p < 2; ++p) {
            __syncthreads();
            if ((wy >> 1) == p) {
#pragma unroll
                for (int mt = 0; mt < 4; ++mt)
#pragma unroll
                    for (int nt = 0; nt < 2; ++nt)
#pragma unroll
                        for (int e = 0; e < 16; ++e) {
                            int cl = wx * 128 + mt * 32 + 4 * hi + 8 * (e >> 2) + (e & 3);
                            int nl = (wy & 1) * 64 + nt * 32 + ln;
                            SM[cl * 136 + nl] = f2bf(acc[mt][nt][e]);
                        }
            }
            __syncthreads();
#pragma unroll
            for (int j = 0; j < 8; ++j) {
                int S = t + 512 * j;              // 4096 short8 = 256 cols x 128 nodes
                int col = S >> 4, nd8 = S & 15;
                short8 v = *(const short8*)(SM + col * 136 + nd8 * 8);
                int gn = n0 + p * 128 + nd8 * 8;
                size_t dst = ((size_t)((c0 >> 5) + (col >> 5)) * 64 + (gn >> 5)) * 1024
                             + (size_t)((((gn >> 3) & 3) * 32 + (col & 31))) * 8;
                *(short8*)(outF + dst) = v;
            }
        }
    }
}

// ---------------------------------------------------------------- GEMM, 128x128 tile, 32x32x16 MFMA, 4 blocks/CU
template<int FG>
__global__ __launch_bounds__(256, 4)
void k_gemm(const u16* __restrict__ A, const u16* __restrict__ Bc,
            u16* __restrict__ outF, u16* __restrict__ outM, int cBlocks) {
    __shared__ u16 SM[16384];
    u16* A0 = SM;            u16* A1 = SM + 4096;
    u16* B0 = SM + 8192;     u16* B1 = SM + 12288;

    int id = blockIdx.x + cBlocks * blockIdx.y;
    int band = cBlocks >> 3;
    int g = id & 7, s = id >> 3;
    int cb = g * band + (s % band);
    int nb = s / band;
    int c0 = cb * 128;
    int n0 = nb * 128;

    int t = threadIdx.x;
    int wave = t >> 6, lane = t & 63;
    int wy = wave & 1, wx = wave >> 1;
    int ln = lane & 31, hi = lane >> 5;
    int l16 = lane * 8;

    const u16* gaP[2];
    const u16* gbP[2];
#pragma unroll
    for (int i = 0; i < 2; ++i) {
        int T = t + 256 * i;
        gaP[i] = A  + ((size_t)((n0 >> 5) + (T >> 7)) * 64) * 1024 + (size_t)(T & 127) * 8;
        gbP[i] = Bc + ((size_t)((c0 >> 5) + (T >> 7)) * 64) * 1024 + (size_t)(T & 127) * 8;
    }

    float16v acc[2][2];
#pragma unroll
    for (int i = 0; i < 2; ++i)
#pragma unroll
        for (int j = 0; j < 2; ++j)
#pragma unroll
            for (int e = 0; e < 16; ++e) acc[i][j][e] = 0.f;

#pragma unroll
    for (int i = 0; i < 2; ++i) { gl2lds16(gaP[i], A0 + (t + 256 * i) * 8); gl2lds16(gbP[i], B0 + (t + 256 * i) * 8); }

#pragma unroll 2
    for (int it = 0; it < 64; ++it) {
        u16* Ac = (it & 1) ? A1 : A0;
        u16* Bs = (it & 1) ? B1 : B0;
        __syncthreads();
        if (it + 1 < 64) {
            int ko = (it + 1) * 1024;
            u16* An = (it & 1) ? A0 : A1;
            u16* Bn = (it & 1) ? B0 : B1;
#pragma unroll
            for (int i = 0; i < 2; ++i) { gl2lds16(gaP[i] + ko, An + (t + 256 * i) * 8); gl2lds16(gbP[i] + ko, Bn + (t + 256 * i) * 8); }
        }
        short8 fa[2][2], fb[2][2];
#pragma unroll
        for (int ks = 0; ks < 2; ++ks) {
#pragma unroll
            for (int mt = 0; mt < 2; ++mt)
                fa[ks][mt] = *(const short8*)(Bs + ((wx * 2 + mt) * 2 + ks) * 512 + l16);
#pragma unroll
            for (int nt = 0; nt < 2; ++nt)
                fb[ks][nt] = *(const short8*)(Ac + ((wy * 2 + nt) * 2 + ks) * 512 + l16);
        }
#pragma unroll
        for (int ks = 0; ks < 2; ++ks)
#pragma unroll
            for (int mt = 0; mt < 2; ++mt)
#pragma unroll
                for (int nt = 0; nt < 2; ++nt)
                    acc[mt][nt] = __builtin_amdgcn_mfma_f32_32x32x16_bf16(fa[ks][mt], fb[ks][nt], acc[mt][nt], 0, 0, 0);
    }

    // m-major direct panel writes
#pragma unroll
    for (int mt = 0; mt < 2; ++mt) {
#pragma unroll
        for (int nt = 0; nt < 2; ++nt) {
            int mg = (n0 >> 5) + wy * 2 + nt;
            int batch = (FG == 4) ? cb : (2 * cb + wx);
            int fg = (FG == 4) ? (wx * 2 + mt) : mt;
            size_t pbase = ((size_t)(batch * 64 + mg) * FG + fg) * 1024;
#pragma unroll
            for (int eq = 0; eq < 4; ++eq) {
                ushort4v pk;
#pragma unroll
                for (int r = 0; r < 4; ++r) pk[r] = f2bf(acc[mt][nt][eq * 4 + r]);
                *(ushort4v*)(outM + pbase + (eq * 32 + ln) * 8 + 4 * hi) = pk;
            }
        }
    }

    // optional f-major panels via LDS transpose
    if (outF) {
        __syncthreads();
#pragma unroll
        for (int p = 0; p < 2; ++p) {
            if (p) __syncthreads();
            if (wx == p) {
#pragma unroll
                for (int mt = 0; mt < 2; ++mt)
#pragma unroll
                    for (int nt = 0; nt < 2; ++nt)
#pragma unroll
                        for (int e = 0; e < 16; ++e) {
                            int cl = mt * 32 + 4 * hi + 8 * (e >> 2) + (e & 3);
                            int nl = wy * 64 + nt * 32 + ln;
                            SM[cl * 136 + nl] = f2bf(acc[mt][nt][e]);
                        }
            }
            __syncthreads();
#pragma unroll
            for (int pp = 0; pp < 4; ++pp) {
                int S = t + 256 * pp;
                int rgl = S >> 9, kgl = (S >> 7) & 3, sl = S & 127;
                int c = sl >> 5, r = sl & 31;
                short8 v = *(const short8*)(SM + (rgl * 32 + r) * 136 + kgl * 32 + c * 8);
                size_t gaddr = ((size_t)((c0 >> 5) + p * 2 + rgl) * 64 + (n0 >> 5) + kgl) * 1024 + sl * 8;
                *(short8*)(outF + gaddr) = v;
            }
        }
    }
}

// ---------------------------------------------------------------- ru projection: 128m x 128o, K=384, fused sigmoid
__global__ __launch_bounds__(256, 3)
void k_proj_ru(const u16* __restrict__ X0m, const u16* __restrict__ X1m, const u16* __restrict__ Ym,
               const u16* __restrict__ Wp, const float* __restrict__ bias, const float* __restrict__ hx,
               u16* __restrict__ RH0f, u16* __restrict__ RH0m, u16* __restrict__ Ut) {
    __shared__ u16 SM[16384];
    u16 *Xa = SM, *Xb = SM + 4096, *Wa = SM + 8192, *Wb = SM + 12288;
    int mb = blockIdx.x, b = blockIdx.y;
    int m0 = mb * 128, mg0 = mb * 4;
    int t = threadIdx.x, wave = t >> 6, lane = t & 63;
    int wx = wave & 1, wyy = wave >> 1;
    int ln = lane & 31, hi = lane >> 5;
    const u16* Xs[3] = {X0m, X1m, Ym};
    int p0 = t >> 7, s0 = t & 127;

    float16v acc[2][2];
#pragma unroll
    for (int i = 0; i < 2; ++i)
#pragma unroll
        for (int j = 0; j < 2; ++j)
#pragma unroll
            for (int e = 0; e < 16; ++e) acc[i][j][e] = 0.f;

    gl2lds16(Xs[0] + ((size_t)((b * 64 + mg0 + p0) * 4)) * 1024 + s0 * 8, Xa + t * 8);
    gl2lds16(Xs[0] + ((size_t)((b * 64 + mg0 + p0 + 2) * 4)) * 1024 + s0 * 8, Xa + (t + 256) * 8);
    gl2lds16(Wp + ((size_t)(p0 * 12)) * 1024 + s0 * 8, Wa + t * 8);
    gl2lds16(Wp + ((size_t)((p0 + 2) * 12)) * 1024 + s0 * 8, Wa + (t + 256) * 8);

    for (int kq = 0; kq < 12; ++kq) {
        u16* Xc = (kq & 1) ? Xb : Xa;
        u16* Wc = (kq & 1) ? Wb : Wa;
        __syncthreads();
        if (kq + 1 < 12) {
            int k2 = kq + 1, kd = k2 >> 2, kg = k2 & 3;
            u16* Xn = (kq & 1) ? Xa : Xb;
            u16* Wn = (kq & 1) ? Wa : Wb;
            const u16* xb = Xs[kd];
            gl2lds16(xb + ((size_t)((b * 64 + mg0 + p0) * 4 + kg)) * 1024 + s0 * 8, Xn + t * 8);
            gl2lds16(xb + ((size_t)((b * 64 + mg0 + p0 + 2) * 4 + kg)) * 1024 + s0 * 8, Xn + (t + 256) * 8);
            gl2lds16(Wp + ((size_t)(p0 * 12 + k2)) * 1024 + s0 * 8, Wn + t * 8);
            gl2lds16(Wp + ((size_t)((p0 + 2) * 12 + k2)) * 1024 + s0 * 8, Wn + (t + 256) * 8);
        }
        short8 fa[2][2], fb[2][2];
#pragma unroll
        for (int ks = 0; ks < 2; ++ks) {
#pragma unroll
            for (int mt = 0; mt < 2; ++mt)
                fa[ks][mt] = *(const short8*)(Xc + ((wx * 2 + mt) * 2 + ks) * 512 + lane * 8);
#pragma unroll
            for (int nt = 0; nt < 2; ++nt)
                fb[ks][nt] = *(const short8*)(Wc + ((wyy * 2 + nt) * 2 + ks) * 512 + lane * 8);
        }
#pragma unroll
        for (int ks = 0; ks < 2; ++ks)
#pragma unroll
            for (int mt = 0; mt < 2; ++mt)
#pragma unroll
                for (int nt = 0; nt < 2; ++nt)
                    acc[mt][nt] = __builtin_amdgcn_mfma_f32_32x32x16_bf16(fa[ks][mt], fb[ks][nt], acc[mt][nt], 0, 0, 0);
    }
    __syncthreads();
    if (wyy == 0) {
#pragma unroll
        for (int mt = 0; mt < 2; ++mt)
#pragma unroll
            for (int nt = 0; nt < 2; ++nt) {
                int o = nt * 32 + ln;
                float bo = bias[o];
                u16 vals[16];
#pragma unroll
                for (int e = 0; e < 16; ++e) {
                    int ml = wx * 64 + mt * 32 + 4 * hi + 8 * (e >> 2) + (e & 3);
                    float sg = sigmoidf_(acc[mt][nt][e] + bo);
                    float hh = hx[((size_t)b * NN + m0 + ml) * 64 + o];
                    vals[e] = f2bf(sg * hh);
                    SM[ml * 76 + o] = vals[e];
                }
#pragma unroll
                for (int eq = 0; eq < 4; ++eq) {
                    ushort4v pk;
#pragma unroll
                    for (int r = 0; r < 4; ++r) pk[r] = vals[eq * 4 + r];
                    size_t addr = ((size_t)(b * 2 + nt) * 64 + mg0 + wx * 2 + mt) * 1024 + (eq * 32 + ln) * 8 + 4 * hi;
                    *(ushort4v*)(RH0f + addr) = pk;
                }
            }
    } else {
#pragma unroll
        for (int mt = 0; mt < 2; ++mt)
#pragma unroll
            for (int nt = 0; nt < 2; ++nt) {
                int og = nt * 32 + ln;
                float bo = bias[64 + og];
#pragma unroll
                for (int e = 0; e < 16; ++e) {
                    int ml = wx * 64 + mt * 32 + 4 * hi + 8 * (e >> 2) + (e & 3);
                    Ut[((size_t)b * NN + m0 + ml) * 64 + og] = f2bf(sigmoidf_(acc[mt][nt][e] + bo));
                }
            }
    }
    __syncthreads();
#pragma unroll
    for (int j = 0; j < 4; ++j) {
        int C = t + 256 * j;
        int p = C >> 7, sl = C & 127;
        int mgl = p >> 1, ug = p & 1;
        int cq = sl >> 5, r = sl & 31;
        short8 v = *(const short8*)(SM + (mgl * 32 + r) * 76 + ug * 32 + cq * 8);
        *(short8*)(RH0m + ((size_t)((b * 64 + mg0 + mgl) * 2 + ug)) * 1024 + sl * 8) = v;
    }
}

// ---------------------------------------------------------------- c projection: 128m x 64o, K=384, fused tanh + combine
__global__ __launch_bounds__(256, 4)
void k_proj_c(const u16* __restrict__ X0m, const u16* __restrict__ X1m, const u16* __restrict__ Ym,
              const u16* __restrict__ RH0m, const u16* __restrict__ RH1m, const u16* __restrict__ Zm,
              const u16* __restrict__ Wp, const float* __restrict__ bias,
              const float* __restrict__ hx, const u16* __restrict__ Ut,
              float* __restrict__ out) {
    __shared__ u16 SM[12288];
    u16 *Xa = SM, *Xb = SM + 4096, *Wa = SM + 8192, *Wb = SM + 10240;
    int mb = blockIdx.x, b = blockIdx.y;
    int m0 = mb * 128, mg0 = mb * 4;
    int t = threadIdx.x, wave = t >> 6, lane = t & 63;
    int wx = wave & 1, wyy = wave >> 1;
    int ln = lane & 31, hi = lane >> 5;
    const u16* Xs[3] = {X0m, X1m, Ym};
    const u16* Rs[3] = {RH0m, RH1m, Zm};
    int p0 = t >> 7, s0 = t & 127;

    float16v acc[2];
#pragma unroll
    for (int i = 0; i < 2; ++i)
#pragma unroll
        for (int e = 0; e < 16; ++e) acc[i][e] = 0.f;

    gl2lds16(Xs[0] + ((size_t)((b * 64 + mg0 + p0) * 4)) * 1024 + s0 * 8, Xa + t * 8);
    gl2lds16(Xs[0] + ((size_t)((b * 64 + mg0 + p0 + 2) * 4)) * 1024 + s0 * 8, Xa + (t + 256) * 8);
    gl2lds16(Wp + ((size_t)(p0 * 12)) * 1024 + s0 * 8, Wa + t * 8);

    for (int kq = 0; kq < 12; ++kq) {
        u16* Xc = (kq & 1) ? Xb : Xa;
        u16* Wc = (kq & 1) ? Wb : Wa;
        __syncthreads();
        if (kq + 1 < 12) {
            int k2 = kq + 1, kd = k2 >> 2, fb2 = (k2 & 3) * 32;
            u16* Xn = (kq & 1) ? Xa : Xb;
            u16* Wn = (kq & 1) ? Wa : Wb;
            const u16* mat; size_t pb0, pb1;
            if (fb2 < 64) {
                mat = Xs[kd];
                pb0 = ((size_t)((b * 64 + mg0 + p0) * 4 + (fb2 >> 5))) * 1024;
                pb1 = ((size_t)((b * 64 + mg0 + p0 + 2) * 4 + (fb2 >> 5))) * 1024;
            } else {
                mat = Rs[kd];
                pb0 = ((size_t)((b * 64 + mg0 + p0) * 2 + ((fb2 >> 5) - 2))) * 1024;
                pb1 = ((size_t)((b * 64 + mg0 + p0 + 2) * 2 + ((fb2 >> 5) - 2))) * 1024;
            }
            gl2lds16(mat + pb0 + s0 * 8, Xn + t * 8);
            gl2lds16(mat + pb1 + s0 * 8, Xn + (t + 256) * 8);
            gl2lds16(Wp + ((size_t)(p0 * 12 + k2)) * 1024 + s0 * 8, Wn + t * 8);
        }
        short8 fa[2][2], fbg[2];
#pragma unroll
        for (int ks = 0; ks < 2; ++ks) {
#pragma unroll
            for (int mt = 0; mt < 2; ++mt)
                fa[ks][mt] = *(const short8*)(Xc + ((wx * 2 + mt) * 2 + ks) * 512 + lane * 8);
            fbg[ks] = *(const short8*)(Wc + (wyy * 2 + ks) * 512 + lane * 8);
        }
#pragma unroll
        for (int ks = 0; ks < 2; ++ks)
#pragma unroll
            for (int mt = 0; mt < 2; ++mt)
                acc[mt] = __builtin_amdgcn_mfma_f32_32x32x16_bf16(fa[ks][mt], fbg[ks], acc[mt], 0, 0, 0);
    }
    int o = wyy * 32 + ln;
    float bo = bias[o];
#pragma unroll
    for (int mt = 0; mt < 2; ++mt)
#pragma unroll
        for (int e = 0; e < 16; ++e) {
            int ml = wx * 64 + mt * 32 + 4 * hi + 8 * (e >> 2) + (e & 3);
            size_t idx = ((size_t)b * NN + m0 + ml) * 64 + o;
            float c = tanhf(acc[mt][e] + bo);
            float u = bf2f(Ut[idx]);
            float hh = hx[idx];
            out[idx] = u * hh + (1.0f - u) * c;
        }
}

// ---------------------------------------------------------------- launch
extern "C" void kernel_launch(void* const* d_in, const int* in_sizes, int n_in,
                              void* d_out, int out_size, void* d_ws, size_t ws_size,
                              hipStream_t stream) {
    const float* x    = (const float*)d_in[0];
    const float* hx   = (const float*)d_in[1];
    const float* adj  = (const float*)d_in[2];
    const float* W_ru = (const float*)d_in[3];
    const float* b_ru = (const float*)d_in[4];
    const float* W_c  = (const float*)d_in[5];
    const float* b_c  = (const float*)d_in[6];
    float* out = (float*)d_out;

    char* ws = (char*)d_ws;
    size_t off = 0;
    auto alloc = [&](size_t bytes) -> void* {
        void* p = ws + off;
        off += (bytes + 255) & ~(size_t)255;
        return p;
    };
    float* d_inv = (float*)alloc((size_t)NN * 4);
    u16* adjT = (u16*)alloc((size_t)NN * NN * 2);
    u16* Wru  = (u16*)alloc((size_t)FD * KT * 2);
    u16* Wc   = (u16*)alloc((size_t)UD * KT * 2);
    u16* X0f = (u16*)alloc((size_t)NB * FD * NN * 2);   // aliased as RH0f after gemm#1
    u16* X1f = (u16*)alloc((size_t)NB * FD * NN * 2);   // aliased as RH1f after gemm#2
    u16* X0m = (u16*)alloc((size_t)NB * FD * NN * 2);
    u16* X1m = (u16*)alloc((size_t)NB * FD * NN * 2);
    u16* Ym  = (u16*)alloc((size_t)NB * FD * NN * 2);
    u16* RH0m = (u16*)alloc((size_t)NB * UD * NN * 2);
    u16* RH1m = (u16*)alloc((size_t)NB * UD * NN * 2);
    u16* Zm   = (u16*)alloc((size_t)NB * UD * NN * 2);
    u16* Ut   = (u16*)alloc((size_t)NB * UD * NN * 2);
    u16* RH0f = X0f;
    u16* RH1f = X1f;

    // merged prep: rownorm | reorderW(ru) | reorderW(c) | xcat  (all independent)
    k_prep<<<dim3(3360), dim3(256), 0, stream>>>(adj, d_inv, W_ru, Wru, W_c, Wc, x, hx, X0f, X0m);
    k_adjT<<<dim3(32, 32), dim3(256), 0, stream>>>(adj, d_inv, adjT);
    // X1 = A@X0 (dual out); Y = A@X1 (m-major only; Chebyshev folded into W)
    // 256^2-tile depth-5 counted-vmcnt kernels: 256 blocks = exactly 1 wave of the 256-CU grid
    k_gemm256<1><<<dim3(256), dim3(512), 0, stream>>>(adjT, X0f, X1f, X1m);
    k_gemm256<0><<<dim3(256), dim3(512), 0, stream>>>(adjT, X1f, nullptr, Ym);
    k_proj_ru<<<dim3(16, NB), dim3(256), 0, stream>>>(X0m, X1m, Ym, Wru, b_ru, hx, RH0f, RH0m, Ut);
    // RH1 = A@RH0 (dual); Z = A@RH1 (m-major only) — N=4096 -> keep 128^2 kernel (full occupancy)
    k_gemm<2><<<dim3(32, 16), dim3(256), 0, stream>>>(adjT, RH0f, RH1f, RH1m, 32);
    k_gemm<2><<<dim3(32, 16), dim3(256), 0, stream>>>(adjT, RH1f, nullptr, Zm, 32);
    k_proj_c<<<dim3(16, NB), dim3(256), 0, stream>>>(X0m, X1m, Ym, RH0m, RH1m, Zm, Wc, b_c, hx, Ut, out);
}

// Round 7
// 422.461 us; speedup vs baseline: 1.0579x; 1.0164x over previous
//
#include <hip/hip_runtime.h>
#include <math.h>

typedef __attribute__((ext_vector_type(8))) short short8;
typedef __attribute__((ext_vector_type(4))) float float4v;
typedef __attribute__((ext_vector_type(16))) float float16v;
typedef __attribute__((ext_vector_type(4))) unsigned short ushort4v;
typedef unsigned short u16;
typedef unsigned int u32;

#define NB 64
#define NN 2048
#define FD 128
#define UD 64
#define KT 384

// ---- PANEL FORMAT ----
// matrix[row][k] -> flat[(rowgrp*KGRPS + kgrp)*1024 + (((k>>3)&3)*32 + (row&31))*8 + (k&7)]
// 32x32 panel = 2KB contiguous; slot order == MFMA fragment order (lane=row, 16B/lane).
// Chebyshev fold: proj uses W0'=W0-W2, W1, W2'=2*W2 so only Y=A@X1 (not X2) is needed.

__device__ __forceinline__ u16 f2bf(float f) {
    unsigned int u = __float_as_uint(f);
    u += 0x7fffu + ((u >> 16) & 1u);
    return (u16)(u >> 16);
}
__device__ __forceinline__ float bf2f(u16 s) {
    return __uint_as_float(((unsigned int)s) << 16);
}
__device__ __forceinline__ float sigmoidf_(float x) {
    return 1.0f / (1.0f + expf(-x));
}
__device__ __forceinline__ void gl2lds16(const u16* g, u16* l) {
    __builtin_amdgcn_global_load_lds((const __attribute__((address_space(1))) unsigned int*)g,
                                     (__attribute__((address_space(3))) unsigned int*)l,
                                     16, 0, 0);
}

// ---------------------------------------------------------------- merged prep
// blocks [0,2048): rownorm | [2048,2240): reorderW ru | [2240,2336): reorderW c | [2336,3360): xcat
__global__ void k_prep(const float* __restrict__ adj, float* __restrict__ d_inv,
                       const float* __restrict__ W_ru, u16* __restrict__ Wru,
                       const float* __restrict__ W_c,  u16* __restrict__ Wc,
                       const float* __restrict__ x, const float* __restrict__ h,
                       u16* __restrict__ X0f, u16* __restrict__ X0m) {
    __shared__ u16 T[128 * 136];
    int bid = blockIdx.x;
    int t = threadIdx.x;
    if (bid < 2048) {
        // ---- rownorm
        int m = bid;
        const float4v* row = (const float4v*)(adj + (size_t)m * NN);
        float s = 0.f;
        for (int i = t; i < NN / 4; i += 256) {
            float4v v = row[i];
            s += v.x + v.y + v.z + v.w;
        }
        float* red = (float*)T;
        for (int off = 32; off; off >>= 1) s += __shfl_down(s, off, 64);
        if ((t & 63) == 0) red[t >> 6] = s;
        __syncthreads();
        if (t == 0) {
            float tt = red[0] + red[1] + red[2] + red[3] + 1.0f;
            d_inv[m] = 1.0f / tt;
        }
        return;
    }
    if (bid < 2336) {
        // ---- reorderW (Chebyshev-folded)
        const float* W; u16* Wt; int OD, idx;
        if (bid < 2240) { W = W_ru; Wt = Wru; OD = FD; idx = (bid - 2048) * 256 + t; }
        else            { W = W_c;  Wt = Wc;  OD = UD; idx = (bid - 2240) * 256 + t; }
        if (idx >= KT * OD) return;
        int o  = idx % OD;
        int kp = idx / OD;
        int kd = kp >> 7, f = kp & 127;
        float v;
        if (kd == 0)      v = W[(size_t)(f * 3 + 0) * OD + o] - W[(size_t)(f * 3 + 2) * OD + o];
        else if (kd == 1) v = W[(size_t)(f * 3 + 1) * OD + o];
        else              v = 2.0f * W[(size_t)(f * 3 + 2) * OD + o];
        size_t dst = ((size_t)(o >> 5) * 12 + (kp >> 5)) * 1024 + (((kp >> 3) & 3) * 32 + (o & 31)) * 8 + (kp & 7);
        Wt[dst] = f2bf(v);
        return;
    }
    // ---- xcat
    int rb = bid - 2336;
    int m0 = (rb & 15) * 128;
    int b  = rb >> 4;
    const float* srcs[2] = { x + (size_t)b * (NN * 64), h + (size_t)b * (NN * 64) };
    for (int s = 0; s < 2; ++s) {
        const float* src = srcs[s];
        for (int p = 0; p < 8; ++p) {
            int idx = t + 256 * p;
            int mi = idx >> 4;
            int f4 = idx & 15;
            float4v v = *(const float4v*)(src + (size_t)(m0 + mi) * 64 + f4 * 4);
            float vv[4] = {v.x, v.y, v.z, v.w};
#pragma unroll
            for (int j = 0; j < 4; ++j)
                T[(s * 64 + f4 * 4 + j) * 136 + mi] = f2bf(vv[j]);
        }
    }
    __syncthreads();
#pragma unroll
    for (int p = 0; p < 8; ++p) {
        int S = t + 256 * p;
        int fgl = S >> 9, kgl = (S >> 7) & 3, s = S & 127;
        int c = s >> 5, r = s & 31;
        short8 v = *(const short8*)(T + (fgl * 32 + r) * 136 + kgl * 32 + c * 8);
        *(short8*)(X0f + ((size_t)(b * 4 + fgl) * 64 + (m0 >> 5) + kgl) * 1024 + s * 8) = v;
    }
#pragma unroll
    for (int p = 0; p < 8; ++p) {
        int S = t + 256 * p;
        int fc = S >> 7;
        int mi = S & 127;
        short8 v;
#pragma unroll
        for (int e = 0; e < 8; ++e) v[e] = (short)T[(fc * 8 + e) * 136 + mi];
        size_t dst = ((size_t)(b * 64 + (m0 >> 5) + (mi >> 5)) * 4 + (fc >> 2)) * 1024
                     + ((fc & 3) * 32 + (mi & 31)) * 8;
        *(short8*)(X0m + dst) = v;
    }
}

// ---------------------------------------------------------------- adjT panels (rows n, k=m)
__global__ void k_adjT(const float* __restrict__ adj, const float* __restrict__ d_inv,
                       u16* __restrict__ adjT) {
    __shared__ u16 T[64 * 72];
    int m0 = blockIdx.x * 64;
    int n0 = blockIdx.y * 64;
    int t = threadIdx.x;
    for (int p = 0; p < 4; ++p) {
        int idx = t + 256 * p;
        int i  = idx >> 4;
        int n4 = idx & 15;
        int m = m0 + i;
        float4v v = *(const float4v*)(adj + (size_t)m * NN + n0 + n4 * 4);
        float di = d_inv[m];
        float vv[4] = {v.x, v.y, v.z, v.w};
#pragma unroll
        for (int j = 0; j < 4; ++j) {
            int n = n0 + n4 * 4 + j;
            float a = vv[j] + ((m == n) ? 1.0f : 0.0f);
            T[(n4 * 4 + j) * 72 + i] = f2bf(a * di);
        }
    }
    __syncthreads();
#pragma unroll
    for (int p = 0; p < 2; ++p) {
        int S = t + 256 * p;
        int rgl = S >> 8, kgl = (S >> 7) & 1, s = S & 127;
        int c = s >> 5, r = s & 31;
        short8 v = *(const short8*)(T + (rgl * 32 + r) * 72 + kgl * 32 + c * 8);
        *(short8*)(adjT + ((size_t)((n0 >> 5) + rgl) * 64 + (m0 >> 5) + kgl) * 1024 + s * 8) = v;
    }
}

// ---------------------------------------------------------------- GEMM 256x256 tile, 8-wave, DEEP counted-vmcnt pipeline
// (unchanged from r6 best: 5-buffer ring, stage 4 ahead, vmcnt(12) steady gate)
template<int HAS_F>
__global__ __launch_bounds__(512, 2)
void k_gemm256(const u16* __restrict__ Ap, const u16* __restrict__ Bc,
               u16* __restrict__ outF, u16* __restrict__ outM) {
    __shared__ __align__(16) u16 SM[81920];   // 5 bufs x (8 col panels + 8 node panels) x 1024
    int bid = blockIdx.x;
    int wxcd = bid >> 3;
    int cb = (bid & 7) * 4 + (wxcd & 3);   // 4 col-blocks per XCD -> X slice L2-resident
    int nb = wxcd >> 2;                    // node blocks stream (adjT from L3, sync'd across XCDs)
    int n0 = nb * 256, c0 = cb * 256;
    int t = threadIdx.x;
    int wave = t >> 6, lane = t & 63;
    int wx = wave >> 2;          // col half (0..1)
    int wy = wave & 3;           // node quarter (0..3)
    int ln = lane & 31, hi = lane >> 5;

    const u16* gA[2];            // cols operand (Bc)
    const u16* gB[2];            // nodes operand (Ap)
    int la[2], lb[2];
#pragma unroll
    for (int i = 0; i < 2; ++i) {
        int idx = i * 512 + t;
        int p = idx >> 7, s = idx & 127;
        gA[i] = Bc + ((size_t)((c0 >> 5) + p) * 64) * 1024 + s * 8;
        gB[i] = Ap + ((size_t)((n0 >> 5) + p) * 64) * 1024 + s * 8;
        la[i] = idx * 8;
        lb[i] = 8192 + idx * 8;
    }

    float16v acc[4][2];
#pragma unroll
    for (int mt = 0; mt < 4; ++mt)
#pragma unroll
        for (int nt = 0; nt < 2; ++nt)
#pragma unroll
            for (int e = 0; e < 16; ++e) acc[mt][nt][e] = 0.f;

    // prologue: stage tiles 0..3 -> bufs 0..3 (16 issues); wait tile0 only (12 in flight)
#pragma unroll
    for (int tt = 0; tt < 4; ++tt) {
#pragma unroll
        for (int i = 0; i < 2; ++i) gl2lds16(gA[i] + tt * 1024, SM + tt * 16384 + la[i]);
#pragma unroll
        for (int i = 0; i < 2; ++i) gl2lds16(gB[i] + tt * 1024, SM + tt * 16384 + lb[i]);
    }
    asm volatile("s_waitcnt vmcnt(12)" ::: "memory");
    __builtin_amdgcn_s_barrier();
    __builtin_amdgcn_sched_barrier(0);

    int rdA = wx * 4096 + lane * 8;          // col panels wx*4+mt
    int rdB = 8192 + wy * 2048 + lane * 8;   // node panels wy*2+nt

    int cur = 0;
    for (int kt = 0; kt < 64; ++kt) {
        u16* buf = SM + cur * 16384;
        int stg = cur + 4; if (stg >= 5) stg -= 5;   // buffer of tile kt-1 (retired at last barrier)
        u16* sbuf = SM + stg * 16384;
        size_t ko = (size_t)(kt + 4) * 1024;

        short8 fa0[4], fb0[2], fa1[4], fb1[2];
#pragma unroll
        for (int mt = 0; mt < 4; ++mt) fa0[mt] = *(const short8*)(buf + rdA + mt * 1024);
#pragma unroll
        for (int nt = 0; nt < 2; ++nt) fb0[nt] = *(const short8*)(buf + rdB + nt * 1024);
        if (kt < 60) {
#pragma unroll
            for (int i = 0; i < 2; ++i) gl2lds16(gA[i] + ko, sbuf + la[i]);
        }
#pragma unroll
        for (int mt = 0; mt < 4; ++mt) fa1[mt] = *(const short8*)(buf + rdA + mt * 1024 + 512);

        __builtin_amdgcn_s_setprio(1);
#pragma unroll
        for (int mt = 0; mt < 4; ++mt)
#pragma unroll
            for (int nt = 0; nt < 2; ++nt)
                acc[mt][nt] = __builtin_amdgcn_mfma_f32_32x32x16_bf16(fa0[mt], fb0[nt], acc[mt][nt], 0, 0, 0);
        __builtin_amdgcn_s_setprio(0);

#pragma unroll
        for (int nt = 0; nt < 2; ++nt) fb1[nt] = *(const short8*)(buf + rdB + nt * 1024 + 512);
        if (kt < 60) {
#pragma unroll
            for (int i = 0; i < 2; ++i) gl2lds16(gB[i] + ko, sbuf + lb[i]);
        }

        __builtin_amdgcn_s_setprio(1);
#pragma unroll
        for (int mt = 0; mt < 4; ++mt)
#pragma unroll
            for (int nt = 0; nt < 2; ++nt)
                acc[mt][nt] = __builtin_amdgcn_mfma_f32_32x32x16_bf16(fa1[mt], fb1[nt], acc[mt][nt], 0, 0, 0);
        __builtin_amdgcn_s_setprio(0);

        if (kt < 60)       asm volatile("s_waitcnt vmcnt(12)" ::: "memory");
        else if (kt == 60) asm volatile("s_waitcnt vmcnt(8)"  ::: "memory");
        else if (kt == 61) asm volatile("s_waitcnt vmcnt(4)"  ::: "memory");
        else if (kt == 62) asm volatile("s_waitcnt vmcnt(0)"  ::: "memory");
        if (kt < 63) {
            __builtin_amdgcn_s_barrier();
            __builtin_amdgcn_sched_barrier(0);
        }
        cur = (cur + 1 == 5) ? 0 : cur + 1;
    }

    // ---- m-major direct panel writes
    int batch0 = cb * 2 + wx;                 // FD=128 -> col half == batch
#pragma unroll
    for (int mt = 0; mt < 4; ++mt) {
#pragma unroll
        for (int nt = 0; nt < 2; ++nt) {
            int mg = (n0 >> 5) + wy * 2 + nt;
            size_t pbase = ((size_t)(batch0 * 64 + mg) * 4 + mt) * 1024;
#pragma unroll
            for (int eq = 0; eq < 4; ++eq) {
                ushort4v pk;
#pragma unroll
                for (int r = 0; r < 4; ++r) pk[r] = f2bf(acc[mt][nt][eq * 4 + r]);
                *(ushort4v*)(outM + pbase + (eq * 32 + ln) * 8 + 4 * hi) = pk;
            }
        }
    }

    // ---- optional f-major panels via LDS transpose
    if (HAS_F) {
#pragma unroll
        for (int p = 0; p < 2; ++p) {
            __syncthreads();
            if ((wy >> 1) == p) {
#pragma unroll
                for (int mt = 0; mt < 4; ++mt)
#pragma unroll
                    for (int nt = 0; nt < 2; ++nt)
#pragma unroll
                        for (int e = 0; e < 16; ++e) {
                            int cl = wx * 128 + mt * 32 + 4 * hi + 8 * (e >> 2) + (e & 3);
                            int nl = (wy & 1) * 64 + nt * 32 + ln;
                            SM[cl * 136 + nl] = f2bf(acc[mt][nt][e]);
                        }
            }
            __syncthreads();
#pragma unroll
            for (int j = 0; j < 8; ++j) {
                int S = t + 512 * j;              // 4096 short8 = 256 cols x 128 nodes
                int col = S >> 4, nd8 = S & 15;
                short8 v = *(const short8*)(SM + col * 136 + nd8 * 8);
                int gn = n0 + p * 128 + nd8 * 8;
                size_t dst = ((size_t)((c0 >> 5) + (col >> 5)) * 64 + (gn >> 5)) * 1024
                             + (size_t)((((gn >> 3) & 3) * 32 + (col & 31))) * 8;
                *(short8*)(outF + dst) = v;
            }
        }
    }
}

// ---------------------------------------------------------------- GEMM, 128x128 tile, 32x32x16 MFMA, 4 blocks/CU
template<int FG>
__global__ __launch_bounds__(256, 4)
void k_gemm(const u16* __restrict__ A, const u16* __restrict__ Bc,
            u16* __restrict__ outF, u16* __restrict__ outM, int cBlocks) {
    __shared__ u16 SM[16384];
    u16* A0 = SM;            u16* A1 = SM + 4096;
    u16* B0 = SM + 8192;     u16* B1 = SM + 12288;

    int id = blockIdx.x + cBlocks * blockIdx.y;
    int band = cBlocks >> 3;
    int g = id & 7, s = id >> 3;
    int cb = g * band + (s % band);
    int nb = s / band;
    int c0 = cb * 128;
    int n0 = nb * 128;

    int t = threadIdx.x;
    int wave = t >> 6, lane = t & 63;
    int wy = wave & 1, wx = wave >> 1;
    int ln = lane & 31, hi = lane >> 5;
    int l16 = lane * 8;

    const u16* gaP[2];
    const u16* gbP[2];
#pragma unroll
    for (int i = 0; i < 2; ++i) {
        int T = t + 256 * i;
        gaP[i] = A  + ((size_t)((n0 >> 5) + (T >> 7)) * 64) * 1024 + (size_t)(T & 127) * 8;
        gbP[i] = Bc + ((size_t)((c0 >> 5) + (T >> 7)) * 64) * 1024 + (size_t)(T & 127) * 8;
    }

    float16v acc[2][2];
#pragma unroll
    for (int i = 0; i < 2; ++i)
#pragma unroll
        for (int j = 0; j < 2; ++j)
#pragma unroll
            for (int e = 0; e < 16; ++e) acc[i][j][e] = 0.f;

#pragma unroll
    for (int i = 0; i < 2; ++i) { gl2lds16(gaP[i], A0 + (t + 256 * i) * 8); gl2lds16(gbP[i], B0 + (t + 256 * i) * 8); }

#pragma unroll 2
    for (int it = 0; it < 64; ++it) {
        u16* Ac = (it & 1) ? A1 : A0;
        u16* Bs = (it & 1) ? B1 : B0;
        __syncthreads();
        if (it + 1 < 64) {
            int ko = (it + 1) * 1024;
            u16* An = (it & 1) ? A0 : A1;
            u16* Bn = (it & 1) ? B0 : B1;
#pragma unroll
            for (int i = 0; i < 2; ++i) { gl2lds16(gaP[i] + ko, An + (t + 256 * i) * 8); gl2lds16(gbP[i] + ko, Bn + (t + 256 * i) * 8); }
        }
        short8 fa[2][2], fb[2][2];
#pragma unroll
        for (int ks = 0; ks < 2; ++ks) {
#pragma unroll
            for (int mt = 0; mt < 2; ++mt)
                fa[ks][mt] = *(const short8*)(Bs + ((wx * 2 + mt) * 2 + ks) * 512 + l16);
#pragma unroll
            for (int nt = 0; nt < 2; ++nt)
                fb[ks][nt] = *(const short8*)(Ac + ((wy * 2 + nt) * 2 + ks) * 512 + l16);
        }
#pragma unroll
        for (int ks = 0; ks < 2; ++ks)
#pragma unroll
            for (int mt = 0; mt < 2; ++mt)
#pragma unroll
                for (int nt = 0; nt < 2; ++nt)
                    acc[mt][nt] = __builtin_amdgcn_mfma_f32_32x32x16_bf16(fa[ks][mt], fb[ks][nt], acc[mt][nt], 0, 0, 0);
    }

    // m-major direct panel writes
#pragma unroll
    for (int mt = 0; mt < 2; ++mt) {
#pragma unroll
        for (int nt = 0; nt < 2; ++nt) {
            int mg = (n0 >> 5) + wy * 2 + nt;
            int batch = (FG == 4) ? cb : (2 * cb + wx);
            int fg = (FG == 4) ? (wx * 2 + mt) : mt;
            size_t pbase = ((size_t)(batch * 64 + mg) * FG + fg) * 1024;
#pragma unroll
            for (int eq = 0; eq < 4; ++eq) {
                ushort4v pk;
#pragma unroll
                for (int r = 0; r < 4; ++r) pk[r] = f2bf(acc[mt][nt][eq * 4 + r]);
                *(ushort4v*)(outM + pbase + (eq * 32 + ln) * 8 + 4 * hi) = pk;
            }
        }
    }

    // optional f-major panels via LDS transpose
    if (outF) {
        __syncthreads();
#pragma unroll
        for (int p = 0; p < 2; ++p) {
            if (p) __syncthreads();
            if (wx == p) {
#pragma unroll
                for (int mt = 0; mt < 2; ++mt)
#pragma unroll
                    for (int nt = 0; nt < 2; ++nt)
#pragma unroll
                        for (int e = 0; e < 16; ++e) {
                            int cl = mt * 32 + 4 * hi + 8 * (e >> 2) + (e & 3);
                            int nl = wy * 64 + nt * 32 + ln;
                            SM[cl * 136 + nl] = f2bf(acc[mt][nt][e]);
                        }
            }
            __syncthreads();
#pragma unroll
            for (int pp = 0; pp < 4; ++pp) {
                int S = t + 256 * pp;
                int rgl = S >> 9, kgl = (S >> 7) & 3, sl = S & 127;
                int c = sl >> 5, r = sl & 31;
                short8 v = *(const short8*)(SM + (rgl * 32 + r) * 136 + kgl * 32 + c * 8);
                size_t gaddr = ((size_t)((c0 >> 5) + p * 2 + rgl) * 64 + (n0 >> 5) + kgl) * 1024 + sl * 8;
                *(short8*)(outF + gaddr) = v;
            }
        }
    }
}

// ---------------------------------------------------------------- ru projection: 128m x 128o, K=384, fused sigmoid
// RING-3 counted-vmcnt K-loop: stage step kq+2 while computing kq; gate vmcnt(4) (one
// step's 4 issues stay in flight across the barrier); drain only at tail. Replaces the
// per-step __syncthreads drain (m97 disease). LDS 48KB x 3 blocks/CU = 144KB.
__global__ __launch_bounds__(256, 3)
void k_proj_ru(const u16* __restrict__ X0m, const u16* __restrict__ X1m, const u16* __restrict__ Ym,
               const u16* __restrict__ Wp, const float* __restrict__ bias, const float* __restrict__ hx,
               u16* __restrict__ RH0f, u16* __restrict__ RH0m, u16* __restrict__ Ut) {
    __shared__ u16 SM[24576];   // X ring 3x4096 | W ring 3x4096 (at +12288)
    int mb = blockIdx.x, b = blockIdx.y;
    int m0 = mb * 128, mg0 = mb * 4;
    int t = threadIdx.x, wave = t >> 6, lane = t & 63;
    int wx = wave & 1, wyy = wave >> 1;
    int ln = lane & 31, hi = lane >> 5;
    const u16* Xs[3] = {X0m, X1m, Ym};
    int p0 = t >> 7, s0 = t & 127;

    float16v acc[2][2];
#pragma unroll
    for (int i = 0; i < 2; ++i)
#pragma unroll
        for (int j = 0; j < 2; ++j)
#pragma unroll
            for (int e = 0; e < 16; ++e) acc[i][j][e] = 0.f;

#define STAGE_RU(Q, XD, WD) { \
    const u16* xb_ = Xs[(Q) >> 2]; \
    gl2lds16(xb_ + ((size_t)((b * 64 + mg0 + p0) * 4 + ((Q) & 3))) * 1024 + s0 * 8, (XD) + t * 8); \
    gl2lds16(xb_ + ((size_t)((b * 64 + mg0 + p0 + 2) * 4 + ((Q) & 3))) * 1024 + s0 * 8, (XD) + (t + 256) * 8); \
    gl2lds16(Wp + ((size_t)(p0 * 12 + (Q))) * 1024 + s0 * 8, (WD) + t * 8); \
    gl2lds16(Wp + ((size_t)((p0 + 2) * 12 + (Q))) * 1024 + s0 * 8, (WD) + (t + 256) * 8); }

    // prologue: stage steps 0,1 (8 issues); gate step0 (4 left in flight)
    STAGE_RU(0, SM,        SM + 12288);
    STAGE_RU(1, SM + 4096, SM + 16384);
    asm volatile("s_waitcnt vmcnt(4)" ::: "memory");
    __builtin_amdgcn_s_barrier();
    __builtin_amdgcn_sched_barrier(0);

    int q0 = 0, q1 = 1, q2 = 2;
    for (int kq = 0; kq < 12; ++kq) {
        u16* Xc = SM + q0 * 4096;
        u16* Wc = SM + 12288 + q0 * 4096;
        if (kq + 2 < 12) STAGE_RU(kq + 2, SM + q2 * 4096, SM + 12288 + q2 * 4096);
        short8 fa[2][2], fb[2][2];
#pragma unroll
        for (int ks = 0; ks < 2; ++ks) {
#pragma unroll
            for (int mt = 0; mt < 2; ++mt)
                fa[ks][mt] = *(const short8*)(Xc + ((wx * 2 + mt) * 2 + ks) * 512 + lane * 8);
#pragma unroll
            for (int nt = 0; nt < 2; ++nt)
                fb[ks][nt] = *(const short8*)(Wc + ((wyy * 2 + nt) * 2 + ks) * 512 + lane * 8);
        }
        __builtin_amdgcn_s_setprio(1);
#pragma unroll
        for (int ks = 0; ks < 2; ++ks)
#pragma unroll
            for (int mt = 0; mt < 2; ++mt)
#pragma unroll
                for (int nt = 0; nt < 2; ++nt)
                    acc[mt][nt] = __builtin_amdgcn_mfma_f32_32x32x16_bf16(fa[ks][mt], fb[ks][nt], acc[mt][nt], 0, 0, 0);
        __builtin_amdgcn_s_setprio(0);
        // gate: ensure step kq+1 landed; keep step kq+2's 4 issues in flight
        if (kq < 10)       asm volatile("s_waitcnt vmcnt(4)" ::: "memory");
        else if (kq == 10) asm volatile("s_waitcnt vmcnt(0)" ::: "memory");
        if (kq < 11) {
            __builtin_amdgcn_s_barrier();
            __builtin_amdgcn_sched_barrier(0);
        }
        int tq = q0; q0 = q1; q1 = q2; q2 = tq;
    }
#undef STAGE_RU

    __syncthreads();
    if (wyy == 0) {
#pragma unroll
        for (int mt = 0; mt < 2; ++mt)
#pragma unroll
            for (int nt = 0; nt < 2; ++nt) {
                int o = nt * 32 + ln;
                float bo = bias[o];
                u16 vals[16];
#pragma unroll
                for (int e = 0; e < 16; ++e) {
                    int ml = wx * 64 + mt * 32 + 4 * hi + 8 * (e >> 2) + (e & 3);
                    float sg = sigmoidf_(acc[mt][nt][e] + bo);
                    float hh = hx[((size_t)b * NN + m0 + ml) * 64 + o];
                    vals[e] = f2bf(sg * hh);
                    SM[ml * 76 + o] = vals[e];
                }
#pragma unroll
                for (int eq = 0; eq < 4; ++eq) {
                    ushort4v pk;
#pragma unroll
                    for (int r = 0; r < 4; ++r) pk[r] = vals[eq * 4 + r];
                    size_t addr = ((size_t)(b * 2 + nt) * 64 + mg0 + wx * 2 + mt) * 1024 + (eq * 32 + ln) * 8 + 4 * hi;
                    *(ushort4v*)(RH0f + addr) = pk;
                }
            }
    } else {
#pragma unroll
        for (int mt = 0; mt < 2; ++mt)
#pragma unroll
            for (int nt = 0; nt < 2; ++nt) {
                int og = nt * 32 + ln;
                float bo = bias[64 + og];
#pragma unroll
                for (int e = 0; e < 16; ++e) {
                    int ml = wx * 64 + mt * 32 + 4 * hi + 8 * (e >> 2) + (e & 3);
                    Ut[((size_t)b * NN + m0 + ml) * 64 + og] = f2bf(sigmoidf_(acc[mt][nt][e] + bo));
                }
            }
    }
    __syncthreads();
#pragma unroll
    for (int j = 0; j < 4; ++j) {
        int C = t + 256 * j;
        int p = C >> 7, sl = C & 127;
        int mgl = p >> 1, ug = p & 1;
        int cq = sl >> 5, r = sl & 31;
        short8 v = *(const short8*)(SM + (mgl * 32 + r) * 76 + ug * 32 + cq * 8);
        *(short8*)(RH0m + ((size_t)((b * 64 + mg0 + mgl) * 2 + ug)) * 1024 + sl * 8) = v;
    }
}

// ---------------------------------------------------------------- c projection: 128m x 64o, K=384, fused tanh + combine
// RING-3 counted-vmcnt K-loop (3 issues/step -> gate vmcnt(3)). LDS 36KB x 4 = 144KB.
__global__ __launch_bounds__(256, 4)
void k_proj_c(const u16* __restrict__ X0m, const u16* __restrict__ X1m, const u16* __restrict__ Ym,
              const u16* __restrict__ RH0m, const u16* __restrict__ RH1m, const u16* __restrict__ Zm,
              const u16* __restrict__ Wp, const float* __restrict__ bias,
              const float* __restrict__ hx, const u16* __restrict__ Ut,
              float* __restrict__ out) {
    __shared__ u16 SM[18432];   // X ring 3x4096 | W ring 3x2048 (at +12288)
    int mb = blockIdx.x, b = blockIdx.y;
    int m0 = mb * 128, mg0 = mb * 4;
    int t = threadIdx.x, wave = t >> 6, lane = t & 63;
    int wx = wave & 1, wyy = wave >> 1;
    int ln = lane & 31, hi = lane >> 5;
    const u16* Xs[3] = {X0m, X1m, Ym};
    const u16* Rs[3] = {RH0m, RH1m, Zm};
    int p0 = t >> 7, s0 = t & 127;

    float16v acc[2];
#pragma unroll
    for (int i = 0; i < 2; ++i)
#pragma unroll
        for (int e = 0; e < 16; ++e) acc[i][e] = 0.f;

#define STAGE_C(Q, XD, WD) { \
    int fb2_ = ((Q) & 3) * 32; \
    const u16* mat_; size_t pb0_, pb1_; \
    if (fb2_ < 64) { \
        mat_ = Xs[(Q) >> 2]; \
        pb0_ = ((size_t)((b * 64 + mg0 + p0) * 4 + (fb2_ >> 5))) * 1024; \
        pb1_ = ((size_t)((b * 64 + mg0 + p0 + 2) * 4 + (fb2_ >> 5))) * 1024; \
    } else { \
        mat_ = Rs[(Q) >> 2]; \
        pb0_ = ((size_t)((b * 64 + mg0 + p0) * 2 + ((fb2_ >> 5) - 2))) * 1024; \
        pb1_ = ((size_t)((b * 64 + mg0 + p0 + 2) * 2 + ((fb2_ >> 5) - 2))) * 1024; \
    } \
    gl2lds16(mat_ + pb0_ + s0 * 8, (XD) + t * 8); \
    gl2lds16(mat_ + pb1_ + s0 * 8, (XD) + (t + 256) * 8); \
    gl2lds16(Wp + ((size_t)(p0 * 12 + (Q))) * 1024 + s0 * 8, (WD) + t * 8); }

    // prologue: stage steps 0,1 (6 issues); gate step0 (3 left in flight)
    STAGE_C(0, SM,        SM + 12288);
    STAGE_C(1, SM + 4096, SM + 14336);
    asm volatile("s_waitcnt vmcnt(3)" ::: "memory");
    __builtin_amdgcn_s_barrier();
    __builtin_amdgcn_sched_barrier(0);

    int q0 = 0, q1 = 1, q2 = 2;
    for (int kq = 0; kq < 12; ++kq) {
        u16* Xc = SM + q0 * 4096;
        u16* Wc = SM + 12288 + q0 * 2048;
        if (kq + 2 < 12) STAGE_C(kq + 2, SM + q2 * 4096, SM + 12288 + q2 * 2048);
        short8 fa[2][2], fbg[2];
#pragma unroll
        for (int ks = 0; ks < 2; ++ks) {
#pragma unroll
            for (int mt = 0; mt < 2; ++mt)
                fa[ks][mt] = *(const short8*)(Xc + ((wx * 2 + mt) * 2 + ks) * 512 + lane * 8);
            fbg[ks] = *(const short8*)(Wc + (wyy * 2 + ks) * 512 + lane * 8);
        }
        __builtin_amdgcn_s_setprio(1);
#pragma unroll
        for (int ks = 0; ks < 2; ++ks)
#pragma unroll
            for (int mt = 0; mt < 2; ++mt)
                acc[mt] = __builtin_amdgcn_mfma_f32_32x32x16_bf16(fa[ks][mt], fbg[ks], acc[mt], 0, 0, 0);
        __builtin_amdgcn_s_setprio(0);
        // gate: ensure step kq+1 landed; keep step kq+2's 3 issues in flight
        if (kq < 10)       asm volatile("s_waitcnt vmcnt(3)" ::: "memory");
        else if (kq == 10) asm volatile("s_waitcnt vmcnt(0)" ::: "memory");
        if (kq < 11) {
            __builtin_amdgcn_s_barrier();
            __builtin_amdgcn_sched_barrier(0);
        }
        int tq = q0; q0 = q1; q1 = q2; q2 = tq;
    }
#undef STAGE_C

    int o = wyy * 32 + ln;
    float bo = bias[o];
#pragma unroll
    for (int mt = 0; mt < 2; ++mt)
#pragma unroll
        for (int e = 0; e < 16; ++e) {
            int ml = wx * 64 + mt * 32 + 4 * hi + 8 * (e >> 2) + (e & 3);
            size_t idx = ((size_t)b * NN + m0 + ml) * 64 + o;
            float c = tanhf(acc[mt][e] + bo);
            float u = bf2f(Ut[idx]);
            float hh = hx[idx];
            out[idx] = u * hh + (1.0f - u) * c;
        }
}

// ---------------------------------------------------------------- launch
extern "C" void kernel_launch(void* const* d_in, const int* in_sizes, int n_in,
                              void* d_out, int out_size, void* d_ws, size_t ws_size,
                              hipStream_t stream) {
    const float* x    = (const float*)d_in[0];
    const float* hx   = (const float*)d_in[1];
    const float* adj  = (const float*)d_in[2];
    const float* W_ru = (const float*)d_in[3];
    const float* b_ru = (const float*)d_in[4];
    const float* W_c  = (const float*)d_in[5];
    const float* b_c  = (const float*)d_in[6];
    float* out = (float*)d_out;

    char* ws = (char*)d_ws;
    size_t off = 0;
    auto alloc = [&](size_t bytes) -> void* {
        void* p = ws + off;
        off += (bytes + 255) & ~(size_t)255;
        return p;
    };
    float* d_inv = (float*)alloc((size_t)NN * 4);
    u16* adjT = (u16*)alloc((size_t)NN * NN * 2);
    u16* Wru  = (u16*)alloc((size_t)FD * KT * 2);
    u16* Wc   = (u16*)alloc((size_t)UD * KT * 2);
    u16* X0f = (u16*)alloc((size_t)NB * FD * NN * 2);   // aliased as RH0f after gemm#1
    u16* X1f = (u16*)alloc((size_t)NB * FD * NN * 2);   // aliased as RH1f after gemm#2
    u16* X0m = (u16*)alloc((size_t)NB * FD * NN * 2);
    u16* X1m = (u16*)alloc((size_t)NB * FD * NN * 2);
    u16* Ym  = (u16*)alloc((size_t)NB * FD * NN * 2);
    u16* RH0m = (u16*)alloc((size_t)NB * UD * NN * 2);
    u16* RH1m = (u16*)alloc((size_t)NB * UD * NN * 2);
    u16* Zm   = (u16*)alloc((size_t)NB * UD * NN * 2);
    u16* Ut   = (u16*)alloc((size_t)NB * UD * NN * 2);
    u16* RH0f = X0f;
    u16* RH1f = X1f;

    // merged prep: rownorm | reorderW(ru) | reorderW(c) | xcat  (all independent)
    k_prep<<<dim3(3360), dim3(256), 0, stream>>>(adj, d_inv, W_ru, Wru, W_c, Wc, x, hx, X0f, X0m);
    k_adjT<<<dim3(32, 32), dim3(256), 0, stream>>>(adj, d_inv, adjT);
    // X1 = A@X0 (dual out); Y = A@X1 (m-major only; Chebyshev folded into W)
    k_gemm256<1><<<dim3(256), dim3(512), 0, stream>>>(adjT, X0f, X1f, X1m);
    k_gemm256<0><<<dim3(256), dim3(512), 0, stream>>>(adjT, X1f, nullptr, Ym);
    k_proj_ru<<<dim3(16, NB), dim3(256), 0, stream>>>(X0m, X1m, Ym, Wru, b_ru, hx, RH0f, RH0m, Ut);
    // RH1 = A@RH0 (dual); Z = A@RH1 (m-major only)
    k_gemm<2><<<dim3(32, 16), dim3(256), 0, stream>>>(adjT, RH0f, RH1f, RH1m, 32);
    k_gemm<2><<<dim3(32, 16), dim3(256), 0, stream>>>(adjT, RH1f, nullptr, Zm, 32);
    k_proj_c<<<dim3(16, NB), dim3(256), 0, stream>>>(X0m, X1m, Ym, RH0m, RH1m, Zm, Wc, b_c, hx, Ut, out);
}